// Round 1
// baseline (7062.604 us; speedup 1.0000x reference)
//
#include <hip/hip_runtime.h>
#include <hip/hip_bf16.h>

// ---------------------------------------------------------------------------
// globalAttention: b=16 t=7 c=64 h=w=64, P=8  ->  112 frames, S=448, D=4096
// Pipeline:
//   1) conv_qk_unfold : depthwise 3x3 conv (q,k) -> bf16 Q,K in [b][s][d]
//   2) conv_v_unfold  : dense 3x3 conv (v)       -> bf16 V   in [b][s][d]
//   3) gemm_qk        : ATTN[b][s][u] = (1/64) * sum_d Q K   (fp32)
//   4) softmax_rows   : row softmax over u
//   5) gemm_pv        : FEAT (fold8 layout) = ATTN @ V
//   6) conv_c_residual: dense 3x3 conv + bias + x -> d_out
// Workspace (bytes): Qb[58.7M] Kb[58.7M] Vb[58.7M] ATTN[12.8M]; FEAT(fp32,
// 117.4MB) aliases Qb+Kb (dead after gemm_qk). Total required ~189 MB.
// ---------------------------------------------------------------------------

namespace {
constexpr int NFR = 112;
constexpr int T_  = 7;
constexpr int B_  = 16;
constexpr int C_  = 64;
constexpr int H_  = 64;
constexpr int W_  = 64;
constexpr int S_  = 448;
constexpr int D_  = 4096;
constexpr size_t QKV_E  = (size_t)B_ * S_ * D_;   // 29,360,128 elements
}

__device__ __forceinline__ float bfu2f(unsigned short u) {
    union { unsigned int i; float f; } v; v.i = ((unsigned int)u) << 16; return v.f;
}

// ---------------- 1) depthwise conv q,k + unfold/rearr -> bf16 [b][s][d] ----
__global__ __launch_bounds__(256) void conv_qk_unfold(
    const float* __restrict__ x,
    const float* __restrict__ wq, const float* __restrict__ bq,
    const float* __restrict__ wk, const float* __restrict__ bk,
    __hip_bfloat16* __restrict__ Q, __hip_bfloat16* __restrict__ K)
{
    int idx = blockIdx.x * 256 + threadIdx.x;      // NFR*C*H*W = 29,360,128
    int xx = idx & 63;
    int yy = (idx >> 6) & 63;
    int c  = (idx >> 12) & 63;
    int f  = idx >> 18;
    const float* xp = x + ((size_t)f * C_ + c) * (H_ * W_);
    float accq = bq[c], acck = bk[c];
    #pragma unroll
    for (int dy = -1; dy <= 1; ++dy) {
        int Y = yy + dy; if ((unsigned)Y >= (unsigned)H_) continue;
        #pragma unroll
        for (int dx = -1; dx <= 1; ++dx) {
            int X = xx + dx; if ((unsigned)X >= (unsigned)W_) continue;
            float v = xp[Y * W_ + X];
            float w1 = wq[c * 9 + (dy + 1) * 3 + (dx + 1)];
            float w2 = wk[c * 9 + (dy + 1) * 3 + (dx + 1)];
            accq += v * w1;
            acck += v * w2;
        }
    }
    int b = f / T_, tt = f % T_;
    int s = tt * 64 + ((yy >> 3) << 3) + (xx >> 3);
    int d = (c << 6) + ((yy & 7) << 3) + (xx & 7);
    size_t o = ((size_t)b * S_ + s) * D_ + d;
    Q[o] = __float2bfloat16(accq);
    K[o] = __float2bfloat16(acck);
}

// ---------------- 2) dense conv v + unfold/rearr -> bf16 [b][s][d] ----------
__global__ __launch_bounds__(256) void conv_v_unfold(
    const float* __restrict__ x,
    const float* __restrict__ wv, const float* __restrict__ bv,
    __hip_bfloat16* __restrict__ V)
{
    __shared__ float ws[C_ * 9];     // 576 floats: weights for this co
    __shared__ float xs[6][W_];      // 6 input rows (4 outputs + halo)
    int f  = blockIdx.z;
    int co = blockIdx.y;
    int y0 = blockIdx.x * 4;
    int tx = threadIdx.x & 63;
    int ty = threadIdx.x >> 6;       // 0..3

    for (int i = threadIdx.x; i < C_ * 9; i += 256) ws[i] = wv[co * C_ * 9 + i];

    float acc = bv[co];
    for (int ci = 0; ci < C_; ++ci) {
        __syncthreads();
        const float* xp = x + ((size_t)f * C_ + ci) * (H_ * W_);
        for (int r = threadIdx.x; r < 6 * W_; r += 256) {
            int ry = y0 - 1 + (r >> 6);
            int rx = r & 63;
            xs[r >> 6][rx] = ((unsigned)ry < (unsigned)H_) ? xp[ry * W_ + rx] : 0.f;
        }
        __syncthreads();
        const float* wp = &ws[ci * 9];
        #pragma unroll
        for (int dy = 0; dy < 3; ++dy) {
            const float* row = xs[ty + dy];
            float l = (tx > 0)  ? row[tx - 1] : 0.f;
            float m = row[tx];
            float r = (tx < 63) ? row[tx + 1] : 0.f;
            acc += wp[dy * 3 + 0] * l + wp[dy * 3 + 1] * m + wp[dy * 3 + 2] * r;
        }
    }
    int yy = y0 + ty;
    int b = f / T_, tt = f % T_;
    int s = tt * 64 + ((yy >> 3) << 3) + (tx >> 3);
    int d = (co << 6) + ((yy & 7) << 3) + (tx & 7);
    V[((size_t)b * S_ + s) * D_ + d] = __float2bfloat16(acc);
}

// ---------------- 3) ATTN = scale * Q @ K^T  (per batch, 448x448x4096) ------
__global__ __launch_bounds__(256) void gemm_qk(
    const __hip_bfloat16* __restrict__ Qg,
    const __hip_bfloat16* __restrict__ Kg,
    float* __restrict__ ATTN)
{
    int bb = blockIdx.z;
    int m0 = blockIdx.x * 64;
    int n0 = blockIdx.y * 64;
    const unsigned short* A = (const unsigned short*)Qg + (size_t)bb * S_ * D_;
    const unsigned short* B = (const unsigned short*)Kg + (size_t)bb * S_ * D_;
    __shared__ float As[16][64];
    __shared__ float Bs[16][64];
    int id   = threadIdx.x;
    int la_m = id >> 2;           // 0..63
    int la_k = (id & 3) * 4;      // 0,4,8,12
    int tm = id & 15, tn = id >> 4;
    float acc[4][4] = {};
    for (int k0 = 0; k0 < D_; k0 += 16) {
        __syncthreads();
        ushort4 a4 = *(const ushort4*)&A[(size_t)(m0 + la_m) * D_ + k0 + la_k];
        As[la_k + 0][la_m] = bfu2f(a4.x);
        As[la_k + 1][la_m] = bfu2f(a4.y);
        As[la_k + 2][la_m] = bfu2f(a4.z);
        As[la_k + 3][la_m] = bfu2f(a4.w);
        ushort4 b4 = *(const ushort4*)&B[(size_t)(n0 + la_m) * D_ + k0 + la_k];
        Bs[la_k + 0][la_m] = bfu2f(b4.x);
        Bs[la_k + 1][la_m] = bfu2f(b4.y);
        Bs[la_k + 2][la_m] = bfu2f(b4.z);
        Bs[la_k + 3][la_m] = bfu2f(b4.w);
        __syncthreads();
        #pragma unroll
        for (int k = 0; k < 16; ++k) {
            float a[4], b[4];
            *(float4*)a = *(const float4*)&As[k][tm * 4];
            *(float4*)b = *(const float4*)&Bs[k][tn * 4];
            #pragma unroll
            for (int i = 0; i < 4; ++i)
                #pragma unroll
                for (int j = 0; j < 4; ++j)
                    acc[i][j] += a[i] * b[j];
        }
    }
    const float scale = 1.0f / 64.0f;
    #pragma unroll
    for (int i = 0; i < 4; ++i)
        #pragma unroll
        for (int j = 0; j < 4; ++j)
            ATTN[((size_t)bb * S_ + m0 + tm * 4 + i) * S_ + n0 + tn * 4 + j] =
                acc[i][j] * scale;
}

// ---------------- 4) row softmax over u (448) -------------------------------
__global__ __launch_bounds__(64) void softmax_rows(float* __restrict__ ATTN)
{
    size_t row = blockIdx.x;                 // b*S_ + s
    float* p = ATTN + row * S_;
    int lane = threadIdx.x;
    float vals[7];
    float m = -1e30f;
    #pragma unroll
    for (int i = 0; i < 7; ++i) { vals[i] = p[lane + i * 64]; m = fmaxf(m, vals[i]); }
    #pragma unroll
    for (int off = 32; off; off >>= 1) m = fmaxf(m, __shfl_xor(m, off));
    float sum = 0.f;
    #pragma unroll
    for (int i = 0; i < 7; ++i) { vals[i] = __expf(vals[i] - m); sum += vals[i]; }
    #pragma unroll
    for (int off = 32; off; off >>= 1) sum += __shfl_xor(sum, off);
    float inv = 1.f / sum;
    #pragma unroll
    for (int i = 0; i < 7; ++i) p[lane + i * 64] = vals[i] * inv;
}

// ---------------- 5) FEAT(fold8) = ATTN @ V  (448 x 4096 x 448) -------------
__global__ __launch_bounds__(256) void gemm_pv(
    const float* __restrict__ ATTNg,
    const __hip_bfloat16* __restrict__ Vg,
    float* __restrict__ FEAT)
{
    int bb = blockIdx.z;
    int m0 = blockIdx.x * 64;     // s
    int n0 = blockIdx.y * 64;     // d
    const float*          A = ATTNg + (size_t)bb * S_ * S_;
    const unsigned short* B = (const unsigned short*)Vg + (size_t)bb * S_ * D_;
    __shared__ float As[16][64];
    __shared__ float Bs[16][64];
    int id   = threadIdx.x;
    int la_m = id >> 2;
    int la_k = (id & 3) * 4;
    int lb_k = id >> 4;           // 0..15
    int lb_n = (id & 15) * 4;
    int tm = id & 15, tn = id >> 4;
    float acc[4][4] = {};
    for (int k0 = 0; k0 < S_; k0 += 16) {
        __syncthreads();
        float4 a4 = *(const float4*)&A[(size_t)(m0 + la_m) * S_ + k0 + la_k];
        As[la_k + 0][la_m] = a4.x;
        As[la_k + 1][la_m] = a4.y;
        As[la_k + 2][la_m] = a4.z;
        As[la_k + 3][la_m] = a4.w;
        ushort4 b4 = *(const ushort4*)&B[(size_t)(k0 + lb_k) * D_ + n0 + lb_n];
        Bs[lb_k][lb_n + 0] = bfu2f(b4.x);
        Bs[lb_k][lb_n + 1] = bfu2f(b4.y);
        Bs[lb_k][lb_n + 2] = bfu2f(b4.z);
        Bs[lb_k][lb_n + 3] = bfu2f(b4.w);
        __syncthreads();
        #pragma unroll
        for (int k = 0; k < 16; ++k) {
            float a[4], b[4];
            *(float4*)a = *(const float4*)&As[k][tm * 4];
            *(float4*)b = *(const float4*)&Bs[k][tn * 4];
            #pragma unroll
            for (int i = 0; i < 4; ++i)
                #pragma unroll
                for (int j = 0; j < 4; ++j)
                    acc[i][j] += a[i] * b[j];
        }
    }
    // store with fold8: s=(t,nh,nw) d=(c,ki,kj) -> FEAT[f][c][nh*8+ki][nw*8+kj]
    #pragma unroll
    for (int i = 0; i < 4; ++i) {
        int s = m0 + tm * 4 + i;
        int tt = s >> 6, l = s & 63;
        int f  = bb * T_ + tt;
        #pragma unroll
        for (int j = 0; j < 4; ++j) {
            int d = n0 + tn * 4 + j;
            int c = d >> 6, r = d & 63;
            int y  = ((l >> 3) << 3) + (r >> 3);
            int xx = ((l & 7) << 3) + (r & 7);
            FEAT[(((size_t)f * C_ + c) * H_ + y) * W_ + xx] = acc[i][j];
        }
    }
}

// ---------------- 6) dense conv c + bias + residual -> out ------------------
__global__ __launch_bounds__(256) void conv_c_residual(
    const float* __restrict__ FEAT,
    const float* __restrict__ wc, const float* __restrict__ bc,
    const float* __restrict__ xin,
    float* __restrict__ out)
{
    __shared__ float ws[C_ * 9];
    __shared__ float xs[6][W_];
    int f  = blockIdx.z;
    int co = blockIdx.y;
    int y0 = blockIdx.x * 4;
    int tx = threadIdx.x & 63;
    int ty = threadIdx.x >> 6;

    for (int i = threadIdx.x; i < C_ * 9; i += 256) ws[i] = wc[co * C_ * 9 + i];

    float acc = bc[co];
    for (int ci = 0; ci < C_; ++ci) {
        __syncthreads();
        const float* xp = FEAT + ((size_t)f * C_ + ci) * (H_ * W_);
        for (int r = threadIdx.x; r < 6 * W_; r += 256) {
            int ry = y0 - 1 + (r >> 6);
            int rx = r & 63;
            xs[r >> 6][rx] = ((unsigned)ry < (unsigned)H_) ? xp[ry * W_ + rx] : 0.f;
        }
        __syncthreads();
        const float* wp = &ws[ci * 9];
        #pragma unroll
        for (int dy = 0; dy < 3; ++dy) {
            const float* row = xs[ty + dy];
            float l = (tx > 0)  ? row[tx - 1] : 0.f;
            float m = row[tx];
            float r = (tx < 63) ? row[tx + 1] : 0.f;
            acc += wp[dy * 3 + 0] * l + wp[dy * 3 + 1] * m + wp[dy * 3 + 2] * r;
        }
    }
    int yy = y0 + ty;
    size_t o = (((size_t)f * C_ + co) * H_ + yy) * W_ + tx;
    out[o] = acc + xin[o];
}

// ---------------------------------------------------------------------------
extern "C" void kernel_launch(void* const* d_in, const int* in_sizes, int n_in,
                              void* d_out, int out_size, void* d_ws, size_t ws_size,
                              hipStream_t stream)
{
    const float* x  = (const float*)d_in[0];
    const float* wq = (const float*)d_in[1];
    const float* bq = (const float*)d_in[2];
    const float* wk = (const float*)d_in[3];
    const float* bk = (const float*)d_in[4];
    const float* wv = (const float*)d_in[5];
    const float* bv = (const float*)d_in[6];
    const float* wc = (const float*)d_in[7];
    const float* bc = (const float*)d_in[8];
    float* out = (float*)d_out;

    // workspace layout (see header comment): needs ~189 MB
    __hip_bfloat16* Qb = (__hip_bfloat16*)d_ws;
    __hip_bfloat16* Kb = Qb + QKV_E;
    __hip_bfloat16* Vb = Kb + QKV_E;
    float* ATTN = (float*)(Vb + QKV_E);
    float* FEAT = (float*)d_ws;            // aliases Qb+Kb (dead after gemm_qk)

    int tot = NFR * C_ * H_ * W_;
    conv_qk_unfold<<<tot / 256, 256, 0, stream>>>(x, wq, bq, wk, bk, Qb, Kb);
    conv_v_unfold<<<dim3(16, C_, NFR), 256, 0, stream>>>(x, wv, bv, Vb);
    gemm_qk<<<dim3(7, 7, B_), 256, 0, stream>>>(Qb, Kb, ATTN);
    softmax_rows<<<B_ * S_, 64, 0, stream>>>(ATTN);
    gemm_pv<<<dim3(7, 64, B_), 256, 0, stream>>>(ATTN, Vb, FEAT);
    conv_c_residual<<<dim3(16, C_, NFR), 256, 0, stream>>>(FEAT, wc, bc, x, out);
}

// Round 2
// 1272.797 us; speedup vs baseline: 5.5489x; 5.5489x over previous
//
#include <hip/hip_runtime.h>
#include <hip/hip_bf16.h>

// ---------------------------------------------------------------------------
// globalAttention: b=16 t=7 c=64 h=w=64, P=8  ->  112 frames, S=448, D=4096
//   1) prep_w x2      : wv,wc fp32 [co][ci][3][3] -> bf16 Wt[r][co][ci]
//   2) conv_qk_unfold : depthwise 3x3 conv (q,k) -> bf16 Q,K in [b][s][d]
//   3) conv_mfma<V>   : dense conv v via MFMA implicit GEMM -> bf16 V [b][s][d]
//   4) gemm_qk        : ATTN = (1/64) Q K^T   (fp32)
//   5) softmax_rows
//   6) gemm_pv        : FEAT (frame layout, bf16) = ATTN @ V
//   7) conv_mfma<C>   : dense conv c via MFMA + bias + residual -> d_out
// Workspace: Qb[58.7M] Kb[58.7M] Vb[58.7M] ATTN[12.8M] Wt_v[72K] Wt_c[72K]
// FEAT(bf16, 58.7M) aliases Qb (dead after gemm_qk). Total ~180.4 MiB.
// ---------------------------------------------------------------------------

namespace {
constexpr int NFR = 112;
constexpr int T_  = 7;
constexpr int B_  = 16;
constexpr int C_  = 64;
constexpr int H_  = 64;
constexpr int W_  = 64;
constexpr int S_  = 448;
constexpr int D_  = 4096;
constexpr size_t QKV_E = (size_t)B_ * S_ * D_;   // 29,360,128 elements
constexpr size_t ATTN_E = (size_t)B_ * S_ * S_;  // 3,211,264 floats
}

typedef __attribute__((ext_vector_type(8))) short short8v;
typedef __attribute__((ext_vector_type(4))) float float4v;

__device__ __forceinline__ float bfu2f(unsigned short u) {
    union { unsigned int i; float f; } v; v.i = ((unsigned int)u) << 16; return v.f;
}
__device__ __forceinline__ unsigned short f2bf(float f) {
    __hip_bfloat16 h = __float2bfloat16(f);
    return *reinterpret_cast<unsigned short*>(&h);
}

// ---------------- 1) weight transpose: [co][ci][3][3] f32 -> [r][co][ci] bf16
__global__ __launch_bounds__(256) void prep_w(const float* __restrict__ wsrc,
                                              __hip_bfloat16* __restrict__ wdst)
{
    int t = blockIdx.x * 256 + threadIdx.x;          // 9*64*64 = 36864
    if (t >= 9 * 64 * 64) return;
    int r = t >> 12, co = (t >> 6) & 63, ci = t & 63;
    wdst[t] = __float2bfloat16(wsrc[(co * 64 + ci) * 9 + r]);
}

// ---------------- 2) depthwise conv q,k + unfold -> bf16 [b][s][d] ----------
__global__ __launch_bounds__(256) void conv_qk_unfold(
    const float* __restrict__ x,
    const float* __restrict__ wq, const float* __restrict__ bq,
    const float* __restrict__ wk, const float* __restrict__ bk,
    __hip_bfloat16* __restrict__ Q, __hip_bfloat16* __restrict__ K)
{
    int idx = blockIdx.x * 256 + threadIdx.x;      // NFR*C*H*W
    int xx = idx & 63;
    int yy = (idx >> 6) & 63;
    int c  = (idx >> 12) & 63;
    int f  = idx >> 18;
    const float* xp = x + ((size_t)f * C_ + c) * (H_ * W_);
    float accq = bq[c], acck = bk[c];
    #pragma unroll
    for (int dy = -1; dy <= 1; ++dy) {
        int Y = yy + dy; if ((unsigned)Y >= (unsigned)H_) continue;
        #pragma unroll
        for (int dx = -1; dx <= 1; ++dx) {
            int X = xx + dx; if ((unsigned)X >= (unsigned)W_) continue;
            float v = xp[Y * W_ + X];
            accq += v * wq[c * 9 + (dy + 1) * 3 + (dx + 1)];
            acck += v * wk[c * 9 + (dy + 1) * 3 + (dx + 1)];
        }
    }
    int b = f / T_, tt = f % T_;
    int s = tt * 64 + ((yy >> 3) << 3) + (xx >> 3);
    int d = (c << 6) + ((yy & 7) << 3) + (xx & 7);
    size_t o = ((size_t)b * S_ + s) * D_ + d;
    Q[o] = __float2bfloat16(accq);
    K[o] = __float2bfloat16(acck);
}

// ---------------- 3/7) dense 3x3 conv as implicit-GEMM MFMA -----------------
// Block: one frame (blockIdx.y), 4 output rows (blockIdx.x*4). 4 waves, one
// row each. M=64 (all co), N=64 (x), K=576 (9 taps x 64 ci), mfma 16x16x32.
// LDS: Xs[row 0..5][xp 0..65][ci 0..63] bf16, swizzled byte ^= (xp&7)<<4.
template<bool IS_V>
__global__ __launch_bounds__(256) void conv_mfma(
    const void* __restrict__ src,                 // IS_V: f32 x ; else bf16 FEAT
    const __hip_bfloat16* __restrict__ Wt,        // [9][64][64] bf16
    const float* __restrict__ bias,
    const float* __restrict__ xin,                // residual input (conv_c)
    void* __restrict__ dst)                       // IS_V: bf16 V ; else f32 out
{
    __shared__ char xs[6 * 66 * 128];
    const int f   = blockIdx.y;
    const int y0  = blockIdx.x * 4;
    const int tid = threadIdx.x;
    const int lane = tid & 63;
    const int w    = tid >> 6;       // wave id = row offset
    const int q    = lane >> 4;      // quarter-wave
    const int l15  = lane & 15;

    // ---- stage: 6 rows x 64 x x 64 ci, 4 ci per thread (8B LDS writes)
    for (int e = tid; e < 6 * 16 * 64; e += 256) {
        int x  = e & 63;
        int cg = (e >> 6) & 15;       // ci group of 4
        int r  = e >> 10;
        int y  = y0 - 1 + r;
        unsigned short p[4];
        if ((unsigned)y < (unsigned)H_) {
            #pragma unroll
            for (int j = 0; j < 4; ++j) {
                size_t gi = (((size_t)f * C_ + cg * 4 + j) * H_ + y) * W_ + x;
                if constexpr (IS_V) p[j] = f2bf(((const float*)src)[gi]);
                else                p[j] = ((const unsigned short*)src)[gi];
            }
        } else { p[0] = p[1] = p[2] = p[3] = 0; }
        int xp = x + 1;
        int byte = (r * 66 + xp) * 128 + ((cg * 8) ^ ((xp & 7) << 4));
        *(uint2*)(xs + byte) = *(uint2*)p;
    }
    // zero the xp=0 and xp=65 halo columns
    for (int e = tid; e < 6 * 16 * 2; e += 256) {
        int side = e & 1;
        int cg   = (e >> 1) & 15;
        int r    = e >> 5;
        int xp   = side ? 65 : 0;
        int byte = (r * 66 + xp) * 128 + ((cg * 8) ^ ((xp & 7) << 4));
        *(uint2*)(xs + byte) = uint2{0u, 0u};
    }
    __syncthreads();

    // ---- K-loop: 9 taps x 2 ci-chunks of 32; 16 mfma per iteration
    float4v acc[4][4] = {};
    for (int r = 0; r < 9; ++r) {
        int ky = r / 3, kx = r - ky * 3;
        int lrow = w + ky;
        #pragma unroll
        for (int kc = 0; kc < 2; ++kc) {
            short8v a[4], b[4];
            #pragma unroll
            for (int mt = 0; mt < 4; ++mt) {
                size_t off = (size_t)(r * 64 + mt * 16 + l15) * 64 + kc * 32 + q * 8;
                a[mt] = *(const short8v*)((const unsigned short*)Wt + off);
            }
            #pragma unroll
            for (int nt = 0; nt < 4; ++nt) {
                int xp = nt * 16 + l15 + kx;
                int byte = (lrow * 66 + xp) * 128 +
                           ((kc * 64 + q * 16) ^ ((xp & 7) << 4));
                b[nt] = *(const short8v*)(xs + byte);
            }
            #pragma unroll
            for (int mt = 0; mt < 4; ++mt)
                #pragma unroll
                for (int nt = 0; nt < 4; ++nt)
                    acc[mt][nt] = __builtin_amdgcn_mfma_f32_16x16x32_bf16(
                        a[mt], b[nt], acc[mt][nt], 0, 0, 0);
        }
    }

    // ---- epilogue: C/D mapping col=lane&15 (x), row=(lane>>4)*4+reg (co)
    const int y = y0 + w;
    const int bb = f / T_, tt = f % T_;
    #pragma unroll
    for (int mt = 0; mt < 4; ++mt) {
        float4 bias4 = *(const float4*)&bias[mt * 16 + q * 4];
        #pragma unroll
        for (int nt = 0; nt < 4; ++nt) {
            int x = nt * 16 + l15;
            #pragma unroll
            for (int j = 0; j < 4; ++j) {
                int co = mt * 16 + q * 4 + j;
                float val = acc[mt][nt][j] + (&bias4.x)[j];
                if constexpr (IS_V) {
                    int s = tt * 64 + ((y >> 3) << 3) + (x >> 3);
                    int d = (co << 6) + ((y & 7) << 3) + (x & 7);
                    ((__hip_bfloat16*)dst)[((size_t)bb * S_ + s) * D_ + d] =
                        __float2bfloat16(val);
                } else {
                    size_t o = (((size_t)f * C_ + co) * H_ + y) * W_ + x;
                    ((float*)dst)[o] = val + xin[o];
                }
            }
        }
    }
}

// ---------------- 4) ATTN = scale * Q @ K^T  (per batch, 448x448x4096) ------
__global__ __launch_bounds__(256) void gemm_qk(
    const __hip_bfloat16* __restrict__ Qg,
    const __hip_bfloat16* __restrict__ Kg,
    float* __restrict__ ATTN)
{
    int bb = blockIdx.z;
    int m0 = blockIdx.x * 64;
    int n0 = blockIdx.y * 64;
    const unsigned short* A = (const unsigned short*)Qg + (size_t)bb * S_ * D_;
    const unsigned short* B = (const unsigned short*)Kg + (size_t)bb * S_ * D_;
    __shared__ float As[16][64];
    __shared__ float Bs[16][64];
    int id   = threadIdx.x;
    int la_m = id >> 2;
    int la_k = (id & 3) * 4;
    int tm = id & 15, tn = id >> 4;
    float acc[4][4] = {};
    for (int k0 = 0; k0 < D_; k0 += 16) {
        __syncthreads();
        ushort4 a4 = *(const ushort4*)&A[(size_t)(m0 + la_m) * D_ + k0 + la_k];
        As[la_k + 0][la_m] = bfu2f(a4.x);
        As[la_k + 1][la_m] = bfu2f(a4.y);
        As[la_k + 2][la_m] = bfu2f(a4.z);
        As[la_k + 3][la_m] = bfu2f(a4.w);
        ushort4 b4 = *(const ushort4*)&B[(size_t)(n0 + la_m) * D_ + k0 + la_k];
        Bs[la_k + 0][la_m] = bfu2f(b4.x);
        Bs[la_k + 1][la_m] = bfu2f(b4.y);
        Bs[la_k + 2][la_m] = bfu2f(b4.z);
        Bs[la_k + 3][la_m] = bfu2f(b4.w);
        __syncthreads();
        #pragma unroll
        for (int k = 0; k < 16; ++k) {
            float a[4], b[4];
            *(float4*)a = *(const float4*)&As[k][tm * 4];
            *(float4*)b = *(const float4*)&Bs[k][tn * 4];
            #pragma unroll
            for (int i = 0; i < 4; ++i)
                #pragma unroll
                for (int j = 0; j < 4; ++j)
                    acc[i][j] += a[i] * b[j];
        }
    }
    const float scale = 1.0f / 64.0f;
    #pragma unroll
    for (int i = 0; i < 4; ++i)
        #pragma unroll
        for (int j = 0; j < 4; ++j)
            ATTN[((size_t)bb * S_ + m0 + tm * 4 + i) * S_ + n0 + tn * 4 + j] =
                acc[i][j] * scale;
}

// ---------------- 5) row softmax over u (448) -------------------------------
__global__ __launch_bounds__(64) void softmax_rows(float* __restrict__ ATTN)
{
    size_t row = blockIdx.x;
    float* p = ATTN + row * S_;
    int lane = threadIdx.x;
    float vals[7];
    float m = -1e30f;
    #pragma unroll
    for (int i = 0; i < 7; ++i) { vals[i] = p[lane + i * 64]; m = fmaxf(m, vals[i]); }
    #pragma unroll
    for (int off = 32; off; off >>= 1) m = fmaxf(m, __shfl_xor(m, off));
    float sum = 0.f;
    #pragma unroll
    for (int i = 0; i < 7; ++i) { vals[i] = __expf(vals[i] - m); sum += vals[i]; }
    #pragma unroll
    for (int off = 32; off; off >>= 1) sum += __shfl_xor(sum, off);
    float inv = 1.f / sum;
    #pragma unroll
    for (int i = 0; i < 7; ++i) p[lane + i * 64] = vals[i] * inv;
}

// ---------------- 6) FEAT(frame layout, bf16) = ATTN @ V --------------------
__global__ __launch_bounds__(256) void gemm_pv(
    const float* __restrict__ ATTNg,
    const __hip_bfloat16* __restrict__ Vg,
    __hip_bfloat16* __restrict__ FEAT)
{
    int bb = blockIdx.z;
    int m0 = blockIdx.x * 64;     // s
    int n0 = blockIdx.y * 64;     // d
    const float*          A = ATTNg + (size_t)bb * S_ * S_;
    const unsigned short* B = (const unsigned short*)Vg + (size_t)bb * S_ * D_;
    __shared__ float As[16][64];
    __shared__ float Bs[16][64];
    int id   = threadIdx.x;
    int la_m = id >> 2;
    int la_k = (id & 3) * 4;
    int lb_k = id >> 4;
    int lb_n = (id & 15) * 4;
    int tm = id & 15, tn = id >> 4;
    float acc[4][4] = {};
    for (int k0 = 0; k0 < S_; k0 += 16) {
        __syncthreads();
        float4 a4 = *(const float4*)&A[(size_t)(m0 + la_m) * S_ + k0 + la_k];
        As[la_k + 0][la_m] = a4.x;
        As[la_k + 1][la_m] = a4.y;
        As[la_k + 2][la_m] = a4.z;
        As[la_k + 3][la_m] = a4.w;
        ushort4 b4 = *(const ushort4*)&B[(size_t)(k0 + lb_k) * D_ + n0 + lb_n];
        Bs[lb_k][lb_n + 0] = bfu2f(b4.x);
        Bs[lb_k][lb_n + 1] = bfu2f(b4.y);
        Bs[lb_k][lb_n + 2] = bfu2f(b4.z);
        Bs[lb_k][lb_n + 3] = bfu2f(b4.w);
        __syncthreads();
        #pragma unroll
        for (int k = 0; k < 16; ++k) {
            float a[4], b[4];
            *(float4*)a = *(const float4*)&As[k][tm * 4];
            *(float4*)b = *(const float4*)&Bs[k][tn * 4];
            #pragma unroll
            for (int i = 0; i < 4; ++i)
                #pragma unroll
                for (int j = 0; j < 4; ++j)
                    acc[i][j] += a[i] * b[j];
        }
    }
    // store into frame layout [f][c][y][x] (what conv_c stages from)
    #pragma unroll
    for (int i = 0; i < 4; ++i) {
        int s = m0 + tm * 4 + i;
        int tt = s >> 6, l = s & 63;
        int f  = bb * T_ + tt;
        #pragma unroll
        for (int j = 0; j < 4; ++j) {
            int d = n0 + tn * 4 + j;
            int c = d >> 6, r = d & 63;
            int y  = ((l >> 3) << 3) + (r >> 3);
            int xx = ((l & 7) << 3) + (r & 7);
            FEAT[(((size_t)f * C_ + c) * H_ + y) * W_ + xx] = __float2bfloat16(acc[i][j]);
        }
    }
}

// ---------------------------------------------------------------------------
extern "C" void kernel_launch(void* const* d_in, const int* in_sizes, int n_in,
                              void* d_out, int out_size, void* d_ws, size_t ws_size,
                              hipStream_t stream)
{
    const float* x  = (const float*)d_in[0];
    const float* wq = (const float*)d_in[1];
    const float* bq = (const float*)d_in[2];
    const float* wk = (const float*)d_in[3];
    const float* bk = (const float*)d_in[4];
    const float* wv = (const float*)d_in[5];
    const float* bv = (const float*)d_in[6];
    const float* wc = (const float*)d_in[7];
    const float* bc = (const float*)d_in[8];
    float* out = (float*)d_out;

    __hip_bfloat16* Qb = (__hip_bfloat16*)d_ws;
    __hip_bfloat16* Kb = Qb + QKV_E;
    __hip_bfloat16* Vb = Kb + QKV_E;
    float* ATTN = (float*)(Vb + QKV_E);
    __hip_bfloat16* Wt_v = (__hip_bfloat16*)(ATTN + ATTN_E);
    __hip_bfloat16* Wt_c = Wt_v + 9 * 64 * 64;
    __hip_bfloat16* FEAT = Qb;              // aliases Qb (dead after gemm_qk)

    prep_w<<<144, 256, 0, stream>>>(wv, Wt_v);
    prep_w<<<144, 256, 0, stream>>>(wc, Wt_c);

    int tot = NFR * C_ * H_ * W_;
    conv_qk_unfold<<<tot / 256, 256, 0, stream>>>(x, wq, bq, wk, bk, Qb, Kb);
    conv_mfma<true><<<dim3(16, NFR), 256, 0, stream>>>(x, Wt_v, bv, nullptr, Vb);
    gemm_qk<<<dim3(7, 7, B_), 256, 0, stream>>>(Qb, Kb, ATTN);
    softmax_rows<<<B_ * S_, 64, 0, stream>>>(ATTN);
    gemm_pv<<<dim3(7, 64, B_), 256, 0, stream>>>(ATTN, Vb, FEAT);
    conv_mfma<false><<<dim3(16, NFR), 256, 0, stream>>>(FEAT, Wt_c, bc, x, out);
}

// Round 3
// 666.438 us; speedup vs baseline: 10.5975x; 1.9099x over previous
//
#include <hip/hip_runtime.h>
#include <hip/hip_bf16.h>

// ---------------------------------------------------------------------------
// globalAttention: b=16 t=7 c=64 h=w=64, P=8  ->  112 frames, S=448, D=4096
//   1) prep_w x2      : wv,wc fp32 [co][ci][3][3] -> bf16 Wt[r][co][ci]
//   2) conv_qk_unfold : depthwise 3x3 conv (q,k) -> bf16 Q,K in [b][s][d]
//   3) conv_mfma<V>   : dense conv v via MFMA implicit GEMM -> bf16 V [b][s][d]
//   4) gemm_qk_mfma   : ATTN = (1/64) Q K^T   (bf16 MFMA, fp32 out)
//   5) softmax_rows   : row softmax -> bf16 P  (P aliases Kb)
//   6) gemm_pv_mfma   : FEAT[f][c][y][x] bf16 = P @ V   (V transposed in LDS)
//   7) conv_mfma<C>   : dense conv c via MFMA + bias + residual -> d_out
// Workspace: Qb[58.7M] Kb[58.7M] Vb[58.7M] ATTN[12.8M] Wt[144K]
// P(bf16) aliases Kb; FEAT(bf16) aliases Qb. Total ~189.5 MiB (same as r2).
// ---------------------------------------------------------------------------

namespace {
constexpr int NFR = 112;
constexpr int T_  = 7;
constexpr int B_  = 16;
constexpr int C_  = 64;
constexpr int H_  = 64;
constexpr int W_  = 64;
constexpr int S_  = 448;
constexpr int D_  = 4096;
constexpr size_t QKV_E = (size_t)B_ * S_ * D_;
constexpr size_t ATTN_E = (size_t)B_ * S_ * S_;
}

typedef __attribute__((ext_vector_type(8))) short short8v;
typedef __attribute__((ext_vector_type(4))) float float4v;

__device__ __forceinline__ float bfu2f(unsigned short u) {
    union { unsigned int i; float f; } v; v.i = ((unsigned int)u) << 16; return v.f;
}
__device__ __forceinline__ unsigned short f2bf(float f) {
    __hip_bfloat16 h = __float2bfloat16(f);
    return *reinterpret_cast<unsigned short*>(&h);
}

// element (r, k) of a 128x64-short tile lives at byte r*128 + ((2k)^((r&7)<<4))
__device__ __forceinline__ short8v frag_ld(const char* ldsb, int r, int kByte) {
    return *(const short8v*)(ldsb + r * 128 + (kByte ^ ((r & 7) << 4)));
}

// stage 128 rows x 64 shorts from g (row stride ldg shorts) into swizzled LDS
template<int NTHR>
__device__ __forceinline__ void stage_tile(char* ldsb, const unsigned short* g,
                                           int ldg, int t) {
    #pragma unroll
    for (int i = 0; i < 1024 / NTHR; ++i) {
        int e = i * NTHR + t;
        int r = e >> 3, c8 = (e & 7) * 8;
        short8v v = *(const short8v*)(g + (size_t)r * ldg + c8);
        *(short8v*)(ldsb + r * 128 + ((c8 * 2) ^ ((r & 7) << 4))) = v;
    }
}

// stage V[u][d] tile (64 u x 128 d) TRANSPOSED into LDS as [d][u] swizzled
__device__ __forceinline__ void stage_vt(char* ldsb, const unsigned short* g, int t) {
    int d0 = (t & 15) * 8;
    int u0 = (t >> 4) * 4;
    short8v r0 = *(const short8v*)(g + (size_t)(u0 + 0) * D_ + d0);
    short8v r1 = *(const short8v*)(g + (size_t)(u0 + 1) * D_ + d0);
    short8v r2 = *(const short8v*)(g + (size_t)(u0 + 2) * D_ + d0);
    short8v r3 = *(const short8v*)(g + (size_t)(u0 + 3) * D_ + d0);
    #pragma unroll
    for (int j = 0; j < 8; ++j) {
        unsigned int lo = (unsigned short)r0[j] | (((unsigned int)(unsigned short)r1[j]) << 16);
        unsigned int hi = (unsigned short)r2[j] | (((unsigned int)(unsigned short)r3[j]) << 16);
        int d = d0 + j;
        int byte = d * 128 + (((unsigned)(u0 * 2)) ^ ((d & 7) << 4));
        *(uint2*)(ldsb + byte) = uint2{lo, hi};
    }
}

// ---------------- 1) weight transpose: [co][ci][3][3] f32 -> [r][co][ci] bf16
__global__ __launch_bounds__(256) void prep_w(const float* __restrict__ wsrc,
                                              __hip_bfloat16* __restrict__ wdst)
{
    int t = blockIdx.x * 256 + threadIdx.x;
    if (t >= 9 * 64 * 64) return;
    int r = t >> 12, co = (t >> 6) & 63, ci = t & 63;
    wdst[t] = __float2bfloat16(wsrc[(co * 64 + ci) * 9 + r]);
}

// ---------------- 2) depthwise conv q,k + unfold -> bf16 [b][s][d] ----------
__global__ __launch_bounds__(256) void conv_qk_unfold(
    const float* __restrict__ x,
    const float* __restrict__ wq, const float* __restrict__ bq,
    const float* __restrict__ wk, const float* __restrict__ bk,
    __hip_bfloat16* __restrict__ Q, __hip_bfloat16* __restrict__ K)
{
    int idx = blockIdx.x * 256 + threadIdx.x;
    int xx = idx & 63;
    int yy = (idx >> 6) & 63;
    int c  = (idx >> 12) & 63;
    int f  = idx >> 18;
    const float* xp = x + ((size_t)f * C_ + c) * (H_ * W_);
    float accq = bq[c], acck = bk[c];
    #pragma unroll
    for (int dy = -1; dy <= 1; ++dy) {
        int Y = yy + dy; if ((unsigned)Y >= (unsigned)H_) continue;
        #pragma unroll
        for (int dx = -1; dx <= 1; ++dx) {
            int X = xx + dx; if ((unsigned)X >= (unsigned)W_) continue;
            float v = xp[Y * W_ + X];
            accq += v * wq[c * 9 + (dy + 1) * 3 + (dx + 1)];
            acck += v * wk[c * 9 + (dy + 1) * 3 + (dx + 1)];
        }
    }
    int b = f / T_, tt = f % T_;
    int s = tt * 64 + ((yy >> 3) << 3) + (xx >> 3);
    int d = (c << 6) + ((yy & 7) << 3) + (xx & 7);
    size_t o = ((size_t)b * S_ + s) * D_ + d;
    Q[o] = __float2bfloat16(accq);
    K[o] = __float2bfloat16(acck);
}

// ---------------- 3/7) dense 3x3 conv as implicit-GEMM MFMA -----------------
template<bool IS_V>
__global__ __launch_bounds__(256) void conv_mfma(
    const void* __restrict__ src,
    const __hip_bfloat16* __restrict__ Wt,
    const float* __restrict__ bias,
    const float* __restrict__ xin,
    void* __restrict__ dst)
{
    __shared__ char xs[6 * 66 * 128];
    const int f   = blockIdx.y;
    const int y0  = blockIdx.x * 4;
    const int tid = threadIdx.x;
    const int lane = tid & 63;
    const int w    = tid >> 6;
    const int q    = lane >> 4;
    const int l15  = lane & 15;

    for (int e = tid; e < 6 * 16 * 64; e += 256) {
        int x  = e & 63;
        int cg = (e >> 6) & 15;
        int r  = e >> 10;
        int y  = y0 - 1 + r;
        unsigned short p[4];
        if ((unsigned)y < (unsigned)H_) {
            #pragma unroll
            for (int j = 0; j < 4; ++j) {
                size_t gi = (((size_t)f * C_ + cg * 4 + j) * H_ + y) * W_ + x;
                if constexpr (IS_V) p[j] = f2bf(((const float*)src)[gi]);
                else                p[j] = ((const unsigned short*)src)[gi];
            }
        } else { p[0] = p[1] = p[2] = p[3] = 0; }
        int xp = x + 1;
        int byte = (r * 66 + xp) * 128 + ((cg * 8) ^ ((xp & 7) << 4));
        *(uint2*)(xs + byte) = *(uint2*)p;
    }
    for (int e = tid; e < 6 * 16 * 2; e += 256) {
        int side = e & 1;
        int cg   = (e >> 1) & 15;
        int r    = e >> 5;
        int xp   = side ? 65 : 0;
        int byte = (r * 66 + xp) * 128 + ((cg * 8) ^ ((xp & 7) << 4));
        *(uint2*)(xs + byte) = uint2{0u, 0u};
    }
    __syncthreads();

    float4v acc[4][4] = {};
    for (int r = 0; r < 9; ++r) {
        int ky = r / 3, kx = r - ky * 3;
        int lrow = w + ky;
        #pragma unroll
        for (int kc = 0; kc < 2; ++kc) {
            short8v a[4], b[4];
            #pragma unroll
            for (int mt = 0; mt < 4; ++mt) {
                size_t off = (size_t)(r * 64 + mt * 16 + l15) * 64 + kc * 32 + q * 8;
                a[mt] = *(const short8v*)((const unsigned short*)Wt + off);
            }
            #pragma unroll
            for (int nt = 0; nt < 4; ++nt) {
                int xp = nt * 16 + l15 + kx;
                int byte = (lrow * 66 + xp) * 128 +
                           ((kc * 64 + q * 16) ^ ((xp & 7) << 4));
                b[nt] = *(const short8v*)(xs + byte);
            }
            #pragma unroll
            for (int mt = 0; mt < 4; ++mt)
                #pragma unroll
                for (int nt = 0; nt < 4; ++nt)
                    acc[mt][nt] = __builtin_amdgcn_mfma_f32_16x16x32_bf16(
                        a[mt], b[nt], acc[mt][nt], 0, 0, 0);
        }
    }

    const int y = y0 + w;
    const int bb = f / T_, tt = f % T_;
    #pragma unroll
    for (int mt = 0; mt < 4; ++mt) {
        float4 bias4 = *(const float4*)&bias[mt * 16 + q * 4];
        #pragma unroll
        for (int nt = 0; nt < 4; ++nt) {
            int x = nt * 16 + l15;
            #pragma unroll
            for (int j = 0; j < 4; ++j) {
                int co = mt * 16 + q * 4 + j;
                float val = acc[mt][nt][j] + (&bias4.x)[j];
                if constexpr (IS_V) {
                    int s = tt * 64 + ((y >> 3) << 3) + (x >> 3);
                    int d = (co << 6) + ((y & 7) << 3) + (x & 7);
                    ((__hip_bfloat16*)dst)[((size_t)bb * S_ + s) * D_ + d] =
                        __float2bfloat16(val);
                } else {
                    size_t o = (((size_t)f * C_ + co) * H_ + y) * W_ + x;
                    ((float*)dst)[o] = val + xin[o];
                }
            }
        }
    }
}

// ---------------- 4) ATTN = (1/64) Q K^T via MFMA ---------------------------
// 128x128 tile, BK=64, 512 thr = 8 waves (2m x 4n), T14 reg-staged LDS.
__global__ __launch_bounds__(512, 2) void gemm_qk_mfma(
    const __hip_bfloat16* __restrict__ Qg,
    const __hip_bfloat16* __restrict__ Kg,
    float* __restrict__ ATTN)
{
    __shared__ alignas(16) char lds[32768];
    char* ldsA = lds;
    char* ldsB = lds + 16384;
    int bid = blockIdx.x;                      // 256 blocks
    int lb  = (bid & 7) * 32 + (bid >> 3);     // XCD-chunked: 2 batches per XCD
    int bb  = lb >> 4;
    int m0  = ((lb >> 2) & 3) * 128;
    int n0  = (lb & 3) * 128;
    const unsigned short* Ag = (const unsigned short*)Qg + (size_t)bb * S_ * D_ + (size_t)m0 * D_;
    const unsigned short* Bg = (const unsigned short*)Kg + (size_t)bb * S_ * D_ + (size_t)n0 * D_;
    int t = threadIdx.x;
    int w = t >> 6, l = t & 63, q = l >> 4, l15 = l & 15;
    int wm = w >> 2, wn = w & 3;
    // per-thread staging coords (2 chunks per tile at 512 threads)
    int r0 = t >> 3, c0 = (t & 7) * 8;         // chunk i=0
    int r1 = 64 + r0;                          // chunk i=1 (e=512+t)
    short8v sA0, sA1, sB0, sB1;
    sA0 = *(const short8v*)(Ag + (size_t)r0 * D_ + c0);
    sA1 = *(const short8v*)(Ag + (size_t)r1 * D_ + c0);
    sB0 = *(const short8v*)(Bg + (size_t)r0 * D_ + c0);
    sB1 = *(const short8v*)(Bg + (size_t)r1 * D_ + c0);

    float4v acc[4][2] = {};
    int swz0 = (c0 * 2) ^ ((r0 & 7) << 4);     // (r1&7)==(r0&7)
    for (int k0 = 0; k0 < D_; k0 += 64) {
        __syncthreads();
        *(short8v*)(ldsA + r0 * 128 + swz0) = sA0;
        *(short8v*)(ldsA + r1 * 128 + swz0) = sA1;
        *(short8v*)(ldsB + r0 * 128 + swz0) = sB0;
        *(short8v*)(ldsB + r1 * 128 + swz0) = sB1;
        if (k0 + 64 < D_) {                    // issue next-tile loads early
            int kn = k0 + 64;
            sA0 = *(const short8v*)(Ag + (size_t)r0 * D_ + kn + c0);
            sA1 = *(const short8v*)(Ag + (size_t)r1 * D_ + kn + c0);
            sB0 = *(const short8v*)(Bg + (size_t)r0 * D_ + kn + c0);
            sB1 = *(const short8v*)(Bg + (size_t)r1 * D_ + kn + c0);
        }
        __syncthreads();
        #pragma unroll
        for (int kc = 0; kc < 2; ++kc) {
            int kB = kc * 64 + q * 16;
            short8v a[4], b[2];
            #pragma unroll
            for (int mt = 0; mt < 4; ++mt) a[mt] = frag_ld(ldsA, wm * 64 + mt * 16 + l15, kB);
            #pragma unroll
            for (int nt = 0; nt < 2; ++nt) b[nt] = frag_ld(ldsB, wn * 32 + nt * 16 + l15, kB);
            #pragma unroll
            for (int mt = 0; mt < 4; ++mt)
                #pragma unroll
                for (int nt = 0; nt < 2; ++nt)
                    acc[mt][nt] = __builtin_amdgcn_mfma_f32_16x16x32_bf16(
                        a[mt], b[nt], acc[mt][nt], 0, 0, 0);
        }
    }
    const float scale = 1.0f / 64.0f;
    #pragma unroll
    for (int mt = 0; mt < 4; ++mt) {
        #pragma unroll
        for (int nt = 0; nt < 2; ++nt) {
            int u = n0 + wn * 32 + nt * 16 + l15;
            #pragma unroll
            for (int j = 0; j < 4; ++j) {
                int s = m0 + wm * 64 + mt * 16 + q * 4 + j;
                if (s < S_ && u < S_)
                    ATTN[((size_t)bb * S_ + s) * S_ + u] = acc[mt][nt][j] * scale;
            }
        }
    }
}

// ---------------- 5) row softmax -> bf16 P ----------------------------------
__global__ __launch_bounds__(64) void softmax_rows(const float* __restrict__ ATTN,
                                                   unsigned short* __restrict__ P)
{
    size_t row = blockIdx.x;
    const float* p = ATTN + row * S_;
    int lane = threadIdx.x;
    float vals[7];
    float m = -1e30f;
    #pragma unroll
    for (int i = 0; i < 7; ++i) { vals[i] = p[lane + i * 64]; m = fmaxf(m, vals[i]); }
    #pragma unroll
    for (int off = 32; off; off >>= 1) m = fmaxf(m, __shfl_xor(m, off));
    float sum = 0.f;
    #pragma unroll
    for (int i = 0; i < 7; ++i) { vals[i] = __expf(vals[i] - m); sum += vals[i]; }
    #pragma unroll
    for (int off = 32; off; off >>= 1) sum += __shfl_xor(sum, off);
    float inv = 1.f / sum;
    #pragma unroll
    for (int i = 0; i < 7; ++i) P[row * S_ + lane + i * 64] = f2bf(vals[i] * inv);
}

// ---------------- 6) FEAT = P @ V via MFMA (V transposed in LDS) ------------
// 128x128 tile, BK=64, 256 thr = 4 waves (2m x 2n).
__global__ __launch_bounds__(256, 2) void gemm_pv_mfma(
    const unsigned short* __restrict__ Pg,
    const __hip_bfloat16* __restrict__ Vg,
    __hip_bfloat16* __restrict__ FEAT)
{
    __shared__ alignas(16) char lds[32768];
    char* ldsA = lds;
    char* ldsB = lds + 16384;
    int bid = blockIdx.x;                       // 2048 blocks
    int lb  = (bid & 7) * 256 + (bid >> 3);
    int bb  = lb >> 7;
    int tl  = lb & 127;
    int m0  = (tl >> 5) * 128;                  // s
    int n0  = (tl & 31) * 128;                  // d
    const unsigned short* Ag = Pg + (size_t)bb * S_ * S_ + (size_t)m0 * S_;
    const unsigned short* Bg = (const unsigned short*)Vg + (size_t)bb * S_ * D_ + n0;
    int t = threadIdx.x;
    int w = t >> 6, l = t & 63, q = l >> 4, l15 = l & 15;
    int wm = w >> 1, wn = w & 1;
    float4v acc[4][4] = {};
    for (int k0 = 0; k0 < S_; k0 += 64) {
        __syncthreads();
        stage_tile<256>(ldsA, Ag + k0, S_, t);
        stage_vt(ldsB, Bg + (size_t)k0 * D_, t);
        __syncthreads();
        #pragma unroll
        for (int kc = 0; kc < 2; ++kc) {
            int kB = kc * 64 + q * 16;
            short8v a[4], b[4];
            #pragma unroll
            for (int mt = 0; mt < 4; ++mt) a[mt] = frag_ld(ldsA, wm * 64 + mt * 16 + l15, kB);
            #pragma unroll
            for (int nt = 0; nt < 4; ++nt) b[nt] = frag_ld(ldsB, wn * 64 + nt * 16 + l15, kB);
            #pragma unroll
            for (int mt = 0; mt < 4; ++mt)
                #pragma unroll
                for (int nt = 0; nt < 4; ++nt)
                    acc[mt][nt] = __builtin_amdgcn_mfma_f32_16x16x32_bf16(
                        a[mt], b[nt], acc[mt][nt], 0, 0, 0);
        }
    }
    // scatter into frame layout [f][c][y][x] bf16
    #pragma unroll
    for (int mt = 0; mt < 4; ++mt) {
        #pragma unroll
        for (int j = 0; j < 4; ++j) {
            int s = m0 + wm * 64 + mt * 16 + q * 4 + j;
            if (s >= S_) continue;
            int f  = bb * T_ + (s >> 6);
            int l6 = s & 63;
            #pragma unroll
            for (int nt = 0; nt < 4; ++nt) {
                int d = n0 + wn * 64 + nt * 16 + l15;
                int c = d >> 6, r = d & 63;
                int y  = ((l6 >> 3) << 3) + (r >> 3);
                int xx = ((l6 & 7) << 3) + (r & 7);
                FEAT[(((size_t)f * C_ + c) * H_ + y) * W_ + xx] =
                    __float2bfloat16(acc[mt][nt][j]);
            }
        }
    }
}

// ---------------------------------------------------------------------------
extern "C" void kernel_launch(void* const* d_in, const int* in_sizes, int n_in,
                              void* d_out, int out_size, void* d_ws, size_t ws_size,
                              hipStream_t stream)
{
    const float* x  = (const float*)d_in[0];
    const float* wq = (const float*)d_in[1];
    const float* bq = (const float*)d_in[2];
    const float* wk = (const float*)d_in[3];
    const float* bk = (const float*)d_in[4];
    const float* wv = (const float*)d_in[5];
    const float* bv = (const float*)d_in[6];
    const float* wc = (const float*)d_in[7];
    const float* bc = (const float*)d_in[8];
    float* out = (float*)d_out;

    __hip_bfloat16* Qb = (__hip_bfloat16*)d_ws;
    __hip_bfloat16* Kb = Qb + QKV_E;
    __hip_bfloat16* Vb = Kb + QKV_E;
    float* ATTN = (float*)(Vb + QKV_E);
    __hip_bfloat16* Wt_v = (__hip_bfloat16*)(ATTN + ATTN_E);
    __hip_bfloat16* Wt_c = Wt_v + 9 * 64 * 64;
    unsigned short* Pb   = (unsigned short*)Kb;   // aliases Kb (dead after qk)
    __hip_bfloat16* FEAT = Qb;                    // aliases Qb (dead after qk)

    prep_w<<<144, 256, 0, stream>>>(wv, Wt_v);
    prep_w<<<144, 256, 0, stream>>>(wc, Wt_c);

    int tot = NFR * C_ * H_ * W_;
    conv_qk_unfold<<<tot / 256, 256, 0, stream>>>(x, wq, bq, wk, bk, Qb, Kb);
    conv_mfma<true><<<dim3(16, NFR), 256, 0, stream>>>(x, Wt_v, bv, nullptr, Vb);
    gemm_qk_mfma<<<256, 512, 0, stream>>>(Qb, Kb, ATTN);
    softmax_rows<<<B_ * S_, 64, 0, stream>>>(ATTN, Pb);
    gemm_pv_mfma<<<2048, 256, 0, stream>>>(Pb, Vb, FEAT);
    conv_mfma<false><<<dim3(16, NFR), 256, 0, stream>>>(FEAT, Wt_c, bc, x, out);
}

// Round 4
// 578.633 us; speedup vs baseline: 12.2057x; 1.1517x over previous
//
#include <hip/hip_runtime.h>
#include <hip/hip_bf16.h>

// ---------------------------------------------------------------------------
// globalAttention: b=16 t=7 c=64 h=w=64, P=8  ->  112 frames, S=448, D=4096
//   1) prep_w x2      : wv,wc fp32 [co][ci][3][3] -> bf16 Wt[r][co][ci]
//   2) conv_qk_unfold2: depthwise 3x3 conv (q,k) -> bf16 Q,K in [b][s][d]
//                       lane=(c&7)*8+(yy&7) so each wave-store is 1KB contig
//   3) conv_mfma<V>   : dense conv v via MFMA implicit GEMM -> bf16 V [b][s][d]
//   4) gemm_qk_mfma   : ATTN = (1/64) Q K^T   (bf16 MFMA, fp32 out)
//   5) softmax_rows   : row softmax -> bf16 P  (P aliases Kb)
//   6) gemm_pv_mfma   : FEAT[f][c][y][x] bf16 = P @ V   (V transposed in LDS)
//   7) conv_mfma<C>   : dense conv c via MFMA + bias + residual -> d_out
// Workspace: Qb[58.7M] Kb[58.7M] Vb[58.7M] ATTN[12.8M] Wt[144K]
// P(bf16) aliases Kb; FEAT(bf16) aliases Qb. Total ~189.5 MiB.
// ---------------------------------------------------------------------------

namespace {
constexpr int NFR = 112;
constexpr int T_  = 7;
constexpr int B_  = 16;
constexpr int C_  = 64;
constexpr int H_  = 64;
constexpr int W_  = 64;
constexpr int S_  = 448;
constexpr int D_  = 4096;
constexpr size_t QKV_E = (size_t)B_ * S_ * D_;
constexpr size_t ATTN_E = (size_t)B_ * S_ * S_;
}

typedef __attribute__((ext_vector_type(8))) short short8v;
typedef __attribute__((ext_vector_type(4))) float float4v;

__device__ __forceinline__ float bfu2f(unsigned short u) {
    union { unsigned int i; float f; } v; v.i = ((unsigned int)u) << 16; return v.f;
}
__device__ __forceinline__ unsigned short f2bf(float f) {
    __hip_bfloat16 h = __float2bfloat16(f);
    return *reinterpret_cast<unsigned short*>(&h);
}

// element (r, k) of a 128x64-short tile lives at byte r*128 + ((2k)^((r&7)<<4))
__device__ __forceinline__ short8v frag_ld(const char* ldsb, int r, int kByte) {
    return *(const short8v*)(ldsb + r * 128 + (kByte ^ ((r & 7) << 4)));
}

// stage 128 rows x 64 shorts from g (row stride ldg shorts) into swizzled LDS
template<int NTHR>
__device__ __forceinline__ void stage_tile(char* ldsb, const unsigned short* g,
                                           int ldg, int t) {
    #pragma unroll
    for (int i = 0; i < 1024 / NTHR; ++i) {
        int e = i * NTHR + t;
        int r = e >> 3, c8 = (e & 7) * 8;
        short8v v = *(const short8v*)(g + (size_t)r * ldg + c8);
        *(short8v*)(ldsb + r * 128 + ((c8 * 2) ^ ((r & 7) << 4))) = v;
    }
}

// stage V[u][d] tile (64 u x 128 d) TRANSPOSED into LDS as [d][u] swizzled
__device__ __forceinline__ void stage_vt(char* ldsb, const unsigned short* g, int t) {
    int d0 = (t & 15) * 8;
    int u0 = (t >> 4) * 4;
    short8v r0 = *(const short8v*)(g + (size_t)(u0 + 0) * D_ + d0);
    short8v r1 = *(const short8v*)(g + (size_t)(u0 + 1) * D_ + d0);
    short8v r2 = *(const short8v*)(g + (size_t)(u0 + 2) * D_ + d0);
    short8v r3 = *(const short8v*)(g + (size_t)(u0 + 3) * D_ + d0);
    #pragma unroll
    for (int j = 0; j < 8; ++j) {
        unsigned int lo = (unsigned short)r0[j] | (((unsigned int)(unsigned short)r1[j]) << 16);
        unsigned int hi = (unsigned short)r2[j] | (((unsigned int)(unsigned short)r3[j]) << 16);
        int d = d0 + j;
        int byte = d * 128 + (((unsigned)(u0 * 2)) ^ ((d & 7) << 4));
        *(uint2*)(ldsb + byte) = uint2{lo, hi};
    }
}

// ---------------- 1) weight transpose: [co][ci][3][3] f32 -> [r][co][ci] bf16
__global__ __launch_bounds__(256) void prep_w(const float* __restrict__ wsrc,
                                              __hip_bfloat16* __restrict__ wdst)
{
    int t = blockIdx.x * 256 + threadIdx.x;
    if (t >= 9 * 64 * 64) return;
    int r = t >> 12, co = (t >> 6) & 63, ci = t & 63;
    wdst[t] = __float2bfloat16(wsrc[(co * 64 + ci) * 9 + r]);
}

// ---------------- 2) depthwise conv q,k + unfold, coalesced stores ----------
// block: (py, octave, frame); lane = cg*8+ky; each lane does one 8-wide patch
// row for px = w, w+4. Wave store = 64 lanes x 16B = 1KB contiguous in Q/K.
__global__ __launch_bounds__(256) void conv_qk_unfold2(
    const float* __restrict__ x,
    const float* __restrict__ wq, const float* __restrict__ bq,
    const float* __restrict__ wk, const float* __restrict__ bk,
    __hip_bfloat16* __restrict__ Q, __hip_bfloat16* __restrict__ K)
{
    int py  = blockIdx.x;          // 0..7
    int oc8 = blockIdx.y;          // 0..7
    int f   = blockIdx.z;          // 0..111
    int t = threadIdx.x;
    int w = t >> 6, lane = t & 63;
    int cg = lane >> 3, ky = lane & 7;
    int c  = oc8 * 8 + cg;
    int yy = py * 8 + ky;
    const float* xp = x + ((size_t)f * C_ + c) * (H_ * W_);
    float wqr[9], wkr[9];
    #pragma unroll
    for (int i = 0; i < 9; ++i) { wqr[i] = wq[c * 9 + i]; wkr[i] = wk[c * 9 + i]; }
    float bqv = bq[c], bkv = bk[c];
    int b = f / T_, tt = f % T_;
    unsigned short* Qp = (unsigned short*)Q;
    unsigned short* Kp = (unsigned short*)K;

    #pragma unroll
    for (int pi = 0; pi < 2; ++pi) {
        int px = w + pi * 4;
        int xb = px * 8;
        float acq[8], ack[8];
        #pragma unroll
        for (int j = 0; j < 8; ++j) { acq[j] = bqv; ack[j] = bkv; }
        #pragma unroll
        for (int dy = 0; dy < 3; ++dy) {
            int Y = yy + dy - 1;
            if ((unsigned)Y >= (unsigned)H_) continue;
            const float* rp = xp + Y * W_ + xb;
            float r[10];
            r[0] = (xb > 0) ? rp[-1] : 0.f;
            #pragma unroll
            for (int j = 0; j < 8; ++j) r[j + 1] = rp[j];
            r[9] = (xb < 56) ? rp[8] : 0.f;
            float w0q = wqr[dy * 3], w1q = wqr[dy * 3 + 1], w2q = wqr[dy * 3 + 2];
            float w0k = wkr[dy * 3], w1k = wkr[dy * 3 + 1], w2k = wkr[dy * 3 + 2];
            #pragma unroll
            for (int j = 0; j < 8; ++j) {
                acq[j] += w0q * r[j] + w1q * r[j + 1] + w2q * r[j + 2];
                ack[j] += w0k * r[j] + w1k * r[j + 1] + w2k * r[j + 2];
            }
        }
        int s = tt * 64 + py * 8 + px;
        size_t off = ((size_t)b * S_ + s) * D_ + (size_t)c * 64 + ky * 8;
        unsigned short pq[8], pk[8];
        #pragma unroll
        for (int j = 0; j < 8; ++j) { pq[j] = f2bf(acq[j]); pk[j] = f2bf(ack[j]); }
        *(short8v*)(Qp + off) = *(const short8v*)pq;
        *(short8v*)(Kp + off) = *(const short8v*)pk;
    }
}

// ---------------- 3/7) dense 3x3 conv as implicit-GEMM MFMA -----------------
template<bool IS_V>
__global__ __launch_bounds__(256) void conv_mfma(
    const void* __restrict__ src,
    const __hip_bfloat16* __restrict__ Wt,
    const float* __restrict__ bias,
    const float* __restrict__ xin,
    void* __restrict__ dst)
{
    __shared__ char xs[6 * 66 * 128];
    const int f   = blockIdx.y;
    const int y0  = blockIdx.x * 4;
    const int tid = threadIdx.x;
    const int lane = tid & 63;
    const int w    = tid >> 6;
    const int q    = lane >> 4;
    const int l15  = lane & 15;

    for (int e = tid; e < 6 * 16 * 64; e += 256) {
        int x  = e & 63;
        int cg = (e >> 6) & 15;
        int r  = e >> 10;
        int y  = y0 - 1 + r;
        unsigned short p[4];
        if ((unsigned)y < (unsigned)H_) {
            #pragma unroll
            for (int j = 0; j < 4; ++j) {
                size_t gi = (((size_t)f * C_ + cg * 4 + j) * H_ + y) * W_ + x;
                if constexpr (IS_V) p[j] = f2bf(((const float*)src)[gi]);
                else                p[j] = ((const unsigned short*)src)[gi];
            }
        } else { p[0] = p[1] = p[2] = p[3] = 0; }
        int xp = x + 1;
        int byte = (r * 66 + xp) * 128 + ((cg * 8) ^ ((xp & 7) << 4));
        *(uint2*)(xs + byte) = *(uint2*)p;
    }
    for (int e = tid; e < 6 * 16 * 2; e += 256) {
        int side = e & 1;
        int cg   = (e >> 1) & 15;
        int r    = e >> 5;
        int xp   = side ? 65 : 0;
        int byte = (r * 66 + xp) * 128 + ((cg * 8) ^ ((xp & 7) << 4));
        *(uint2*)(xs + byte) = uint2{0u, 0u};
    }
    __syncthreads();

    float4v acc[4][4] = {};
    for (int r = 0; r < 9; ++r) {
        int ky = r / 3, kx = r - ky * 3;
        int lrow = w + ky;
        #pragma unroll
        for (int kc = 0; kc < 2; ++kc) {
            short8v a[4], b[4];
            #pragma unroll
            for (int mt = 0; mt < 4; ++mt) {
                size_t off = (size_t)(r * 64 + mt * 16 + l15) * 64 + kc * 32 + q * 8;
                a[mt] = *(const short8v*)((const unsigned short*)Wt + off);
            }
            #pragma unroll
            for (int nt = 0; nt < 4; ++nt) {
                int xp = nt * 16 + l15 + kx;
                int byte = (lrow * 66 + xp) * 128 +
                           ((kc * 64 + q * 16) ^ ((xp & 7) << 4));
                b[nt] = *(const short8v*)(xs + byte);
            }
            #pragma unroll
            for (int mt = 0; mt < 4; ++mt)
                #pragma unroll
                for (int nt = 0; nt < 4; ++nt)
                    acc[mt][nt] = __builtin_amdgcn_mfma_f32_16x16x32_bf16(
                        a[mt], b[nt], acc[mt][nt], 0, 0, 0);
        }
    }

    const int y = y0 + w;
    const int bb = f / T_, tt = f % T_;
    #pragma unroll
    for (int mt = 0; mt < 4; ++mt) {
        float4 bias4 = *(const float4*)&bias[mt * 16 + q * 4];
        #pragma unroll
        for (int nt = 0; nt < 4; ++nt) {
            int x = nt * 16 + l15;
            #pragma unroll
            for (int j = 0; j < 4; ++j) {
                int co = mt * 16 + q * 4 + j;
                float val = acc[mt][nt][j] + (&bias4.x)[j];
                if constexpr (IS_V) {
                    int s = tt * 64 + ((y >> 3) << 3) + (x >> 3);
                    int d = (co << 6) + ((y & 7) << 3) + (x & 7);
                    ((__hip_bfloat16*)dst)[((size_t)bb * S_ + s) * D_ + d] =
                        __float2bfloat16(val);
                } else {
                    size_t o = (((size_t)f * C_ + co) * H_ + y) * W_ + x;
                    ((float*)dst)[o] = val + xin[o];
                }
            }
        }
    }
}

// ---------------- 4) ATTN = (1/64) Q K^T via MFMA ---------------------------
__global__ __launch_bounds__(512, 2) void gemm_qk_mfma(
    const __hip_bfloat16* __restrict__ Qg,
    const __hip_bfloat16* __restrict__ Kg,
    float* __restrict__ ATTN)
{
    __shared__ alignas(16) char lds[32768];
    char* ldsA = lds;
    char* ldsB = lds + 16384;
    int bid = blockIdx.x;
    int lb  = (bid & 7) * 32 + (bid >> 3);
    int bb  = lb >> 4;
    int m0  = ((lb >> 2) & 3) * 128;
    int n0  = (lb & 3) * 128;
    const unsigned short* Ag = (const unsigned short*)Qg + (size_t)bb * S_ * D_ + (size_t)m0 * D_;
    const unsigned short* Bg = (const unsigned short*)Kg + (size_t)bb * S_ * D_ + (size_t)n0 * D_;
    int t = threadIdx.x;
    int w = t >> 6, l = t & 63, q = l >> 4, l15 = l & 15;
    int wm = w >> 2, wn = w & 3;
    int r0 = t >> 3, c0 = (t & 7) * 8;
    int r1 = 64 + r0;
    short8v sA0, sA1, sB0, sB1;
    sA0 = *(const short8v*)(Ag + (size_t)r0 * D_ + c0);
    sA1 = *(const short8v*)(Ag + (size_t)r1 * D_ + c0);
    sB0 = *(const short8v*)(Bg + (size_t)r0 * D_ + c0);
    sB1 = *(const short8v*)(Bg + (size_t)r1 * D_ + c0);

    float4v acc[4][2] = {};
    int swz0 = (c0 * 2) ^ ((r0 & 7) << 4);
    for (int k0 = 0; k0 < D_; k0 += 64) {
        __syncthreads();
        *(short8v*)(ldsA + r0 * 128 + swz0) = sA0;
        *(short8v*)(ldsA + r1 * 128 + swz0) = sA1;
        *(short8v*)(ldsB + r0 * 128 + swz0) = sB0;
        *(short8v*)(ldsB + r1 * 128 + swz0) = sB1;
        if (k0 + 64 < D_) {
            int kn = k0 + 64;
            sA0 = *(const short8v*)(Ag + (size_t)r0 * D_ + kn + c0);
            sA1 = *(const short8v*)(Ag + (size_t)r1 * D_ + kn + c0);
            sB0 = *(const short8v*)(Bg + (size_t)r0 * D_ + kn + c0);
            sB1 = *(const short8v*)(Bg + (size_t)r1 * D_ + kn + c0);
        }
        __syncthreads();
        #pragma unroll
        for (int kc = 0; kc < 2; ++kc) {
            int kB = kc * 64 + q * 16;
            short8v a[4], b[2];
            #pragma unroll
            for (int mt = 0; mt < 4; ++mt) a[mt] = frag_ld(ldsA, wm * 64 + mt * 16 + l15, kB);
            #pragma unroll
            for (int nt = 0; nt < 2; ++nt) b[nt] = frag_ld(ldsB, wn * 32 + nt * 16 + l15, kB);
            #pragma unroll
            for (int mt = 0; mt < 4; ++mt)
                #pragma unroll
                for (int nt = 0; nt < 2; ++nt)
                    acc[mt][nt] = __builtin_amdgcn_mfma_f32_16x16x32_bf16(
                        a[mt], b[nt], acc[mt][nt], 0, 0, 0);
        }
    }
    const float scale = 1.0f / 64.0f;
    #pragma unroll
    for (int mt = 0; mt < 4; ++mt) {
        #pragma unroll
        for (int nt = 0; nt < 2; ++nt) {
            int u = n0 + wn * 32 + nt * 16 + l15;
            #pragma unroll
            for (int j = 0; j < 4; ++j) {
                int s = m0 + wm * 64 + mt * 16 + q * 4 + j;
                if (s < S_ && u < S_)
                    ATTN[((size_t)bb * S_ + s) * S_ + u] = acc[mt][nt][j] * scale;
            }
        }
    }
}

// ---------------- 5) row softmax -> bf16 P ----------------------------------
__global__ __launch_bounds__(64) void softmax_rows(const float* __restrict__ ATTN,
                                                   unsigned short* __restrict__ P)
{
    size_t row = blockIdx.x;
    const float* p = ATTN + row * S_;
    int lane = threadIdx.x;
    float vals[7];
    float m = -1e30f;
    #pragma unroll
    for (int i = 0; i < 7; ++i) { vals[i] = p[lane + i * 64]; m = fmaxf(m, vals[i]); }
    #pragma unroll
    for (int off = 32; off; off >>= 1) m = fmaxf(m, __shfl_xor(m, off));
    float sum = 0.f;
    #pragma unroll
    for (int i = 0; i < 7; ++i) { vals[i] = __expf(vals[i] - m); sum += vals[i]; }
    #pragma unroll
    for (int off = 32; off; off >>= 1) sum += __shfl_xor(sum, off);
    float inv = 1.f / sum;
    #pragma unroll
    for (int i = 0; i < 7; ++i) P[row * S_ + lane + i * 64] = f2bf(vals[i] * inv);
}

// ---------------- 6) FEAT = P @ V via MFMA (V transposed in LDS) ------------
__global__ __launch_bounds__(256, 2) void gemm_pv_mfma(
    const unsigned short* __restrict__ Pg,
    const __hip_bfloat16* __restrict__ Vg,
    __hip_bfloat16* __restrict__ FEAT)
{
    __shared__ alignas(16) char lds[32768];
    char* ldsA = lds;
    char* ldsB = lds + 16384;
    int bid = blockIdx.x;
    int lb  = (bid & 7) * 256 + (bid >> 3);
    int bb  = lb >> 7;
    int tl  = lb & 127;
    int m0  = (tl >> 5) * 128;
    int n0  = (tl & 31) * 128;
    const unsigned short* Ag = Pg + (size_t)bb * S_ * S_ + (size_t)m0 * S_;
    const unsigned short* Bg = (const unsigned short*)Vg + (size_t)bb * S_ * D_ + n0;
    int t = threadIdx.x;
    int w = t >> 6, l = t & 63, q = l >> 4, l15 = l & 15;
    int wm = w >> 1, wn = w & 1;
    float4v acc[4][4] = {};
    for (int k0 = 0; k0 < S_; k0 += 64) {
        __syncthreads();
        stage_tile<256>(ldsA, Ag + k0, S_, t);
        stage_vt(ldsB, Bg + (size_t)k0 * D_, t);
        __syncthreads();
        #pragma unroll
        for (int kc = 0; kc < 2; ++kc) {
            int kB = kc * 64 + q * 16;
            short8v a[4], b[4];
            #pragma unroll
            for (int mt = 0; mt < 4; ++mt) a[mt] = frag_ld(ldsA, wm * 64 + mt * 16 + l15, kB);
            #pragma unroll
            for (int nt = 0; nt < 4; ++nt) b[nt] = frag_ld(ldsB, wn * 64 + nt * 16 + l15, kB);
            #pragma unroll
            for (int mt = 0; mt < 4; ++mt)
                #pragma unroll
                for (int nt = 0; nt < 4; ++nt)
                    acc[mt][nt] = __builtin_amdgcn_mfma_f32_16x16x32_bf16(
                        a[mt], b[nt], acc[mt][nt], 0, 0, 0);
        }
    }
    #pragma unroll
    for (int mt = 0; mt < 4; ++mt) {
        #pragma unroll
        for (int j = 0; j < 4; ++j) {
            int s = m0 + wm * 64 + mt * 16 + q * 4 + j;
            if (s >= S_) continue;
            int f  = bb * T_ + (s >> 6);
            int l6 = s & 63;
            #pragma unroll
            for (int nt = 0; nt < 4; ++nt) {
                int d = n0 + wn * 64 + nt * 16 + l15;
                int c = d >> 6, r = d & 63;
                int y  = ((l6 >> 3) << 3) + (r >> 3);
                int xx = ((l6 & 7) << 3) + (r & 7);
                FEAT[(((size_t)f * C_ + c) * H_ + y) * W_ + xx] =
                    __float2bfloat16(acc[mt][nt][j]);
            }
        }
    }
}

// ---------------------------------------------------------------------------
extern "C" void kernel_launch(void* const* d_in, const int* in_sizes, int n_in,
                              void* d_out, int out_size, void* d_ws, size_t ws_size,
                              hipStream_t stream)
{
    const float* x  = (const float*)d_in[0];
    const float* wq = (const float*)d_in[1];
    const float* bq = (const float*)d_in[2];
    const float* wk = (const float*)d_in[3];
    const float* bk = (const float*)d_in[4];
    const float* wv = (const float*)d_in[5];
    const float* bv = (const float*)d_in[6];
    const float* wc = (const float*)d_in[7];
    const float* bc = (const float*)d_in[8];
    float* out = (float*)d_out;

    __hip_bfloat16* Qb = (__hip_bfloat16*)d_ws;
    __hip_bfloat16* Kb = Qb + QKV_E;
    __hip_bfloat16* Vb = Kb + QKV_E;
    float* ATTN = (float*)(Vb + QKV_E);
    __hip_bfloat16* Wt_v = (__hip_bfloat16*)(ATTN + ATTN_E);
    __hip_bfloat16* Wt_c = Wt_v + 9 * 64 * 64;
    unsigned short* Pb   = (unsigned short*)Kb;   // aliases Kb (dead after qk)
    __hip_bfloat16* FEAT = Qb;                    // aliases Qb (dead after qk)

    prep_w<<<144, 256, 0, stream>>>(wv, Wt_v);
    prep_w<<<144, 256, 0, stream>>>(wc, Wt_c);

    conv_qk_unfold2<<<dim3(8, 8, NFR), 256, 0, stream>>>(x, wq, bq, wk, bk, Qb, Kb);
    conv_mfma<true><<<dim3(16, NFR), 256, 0, stream>>>(x, Wt_v, bv, nullptr, Vb);
    gemm_qk_mfma<<<256, 512, 0, stream>>>(Qb, Kb, ATTN);
    softmax_rows<<<B_ * S_, 64, 0, stream>>>(ATTN, Pb);
    gemm_pv_mfma<<<2048, 256, 0, stream>>>(Pb, Vb, FEAT);
    conv_mfma<false><<<dim3(16, NFR), 256, 0, stream>>>(FEAT, Wt_c, bc, x, out);
}

// Round 5
// 542.378 us; speedup vs baseline: 13.0216x; 1.0668x over previous
//
#include <hip/hip_runtime.h>
#include <hip/hip_bf16.h>

// ---------------------------------------------------------------------------
// globalAttention: b=16 t=7 c=64 h=w=64, P=8  ->  112 frames, S=448, D=4096
//   1) prep_w x2      : wv,wc fp32 [co][ci][3][3] -> bf16 Wt[r][co][ci]
//   2) conv_qk_unfold2: depthwise 3x3 conv (q,k) -> bf16 Q,K, 1KB wave stores
//   3) conv_mfma2<V>  : dense conv v, MFMA implicit GEMM, Wt staged in LDS,
//                       8-row bands, M=128(2rows x 64x) N=64co per wave
//   4) gemm_qk_mfma   : ATTN = (1/64) Q K^T   (bf16 MFMA, fp32 out)
//   5) softmax_rows   : row softmax -> bf16 P  (P aliases Kb)
//   6) gemm_pv_mfma   : FEAT[f][c][y][x] bf16 = P @ V   (V transposed in LDS)
//   7) conv_mfma2<C>  : dense conv c + bias + residual -> d_out (float4 stores)
// Workspace: Qb[58.7M] Kb[58.7M] Vb[58.7M] ATTN[12.8M] Wt[144K]
// P(bf16) aliases Kb; FEAT(bf16) aliases Qb. Total ~189.5 MiB.
// ---------------------------------------------------------------------------

namespace {
constexpr int NFR = 112;
constexpr int T_  = 7;
constexpr int B_  = 16;
constexpr int C_  = 64;
constexpr int H_  = 64;
constexpr int W_  = 64;
constexpr int S_  = 448;
constexpr int D_  = 4096;
constexpr size_t QKV_E = (size_t)B_ * S_ * D_;
constexpr size_t ATTN_E = (size_t)B_ * S_ * S_;
}

typedef __attribute__((ext_vector_type(8))) short short8v;
typedef __attribute__((ext_vector_type(4))) float float4v;

__device__ __forceinline__ float bfu2f(unsigned short u) {
    union { unsigned int i; float f; } v; v.i = ((unsigned int)u) << 16; return v.f;
}
__device__ __forceinline__ unsigned short f2bf(float f) {
    __hip_bfloat16 h = __float2bfloat16(f);
    return *reinterpret_cast<unsigned short*>(&h);
}

// element (r, k) of a Rx64-short tile lives at byte r*128 + ((2k)^((r&7)<<4))
__device__ __forceinline__ short8v frag_ld(const char* ldsb, int r, int kByte) {
    return *(const short8v*)(ldsb + r * 128 + (kByte ^ ((r & 7) << 4)));
}

// stage 128 rows x 64 shorts from g (row stride ldg shorts) into swizzled LDS
template<int NTHR>
__device__ __forceinline__ void stage_tile(char* ldsb, const unsigned short* g,
                                           int ldg, int t) {
    #pragma unroll
    for (int i = 0; i < 1024 / NTHR; ++i) {
        int e = i * NTHR + t;
        int r = e >> 3, c8 = (e & 7) * 8;
        short8v v = *(const short8v*)(g + (size_t)r * ldg + c8);
        *(short8v*)(ldsb + r * 128 + ((c8 * 2) ^ ((r & 7) << 4))) = v;
    }
}

// stage V[u][d] tile (64 u x 128 d) TRANSPOSED into LDS as [d][u] swizzled
__device__ __forceinline__ void stage_vt(char* ldsb, const unsigned short* g, int t) {
    int d0 = (t & 15) * 8;
    int u0 = (t >> 4) * 4;
    short8v r0 = *(const short8v*)(g + (size_t)(u0 + 0) * D_ + d0);
    short8v r1 = *(const short8v*)(g + (size_t)(u0 + 1) * D_ + d0);
    short8v r2 = *(const short8v*)(g + (size_t)(u0 + 2) * D_ + d0);
    short8v r3 = *(const short8v*)(g + (size_t)(u0 + 3) * D_ + d0);
    #pragma unroll
    for (int j = 0; j < 8; ++j) {
        unsigned int lo = (unsigned short)r0[j] | (((unsigned int)(unsigned short)r1[j]) << 16);
        unsigned int hi = (unsigned short)r2[j] | (((unsigned int)(unsigned short)r3[j]) << 16);
        int d = d0 + j;
        int byte = d * 128 + (((unsigned)(u0 * 2)) ^ ((d & 7) << 4));
        *(uint2*)(ldsb + byte) = uint2{lo, hi};
    }
}

// ---------------- 1) weight transpose: [co][ci][3][3] f32 -> [r][co][ci] bf16
__global__ __launch_bounds__(256) void prep_w(const float* __restrict__ wsrc,
                                              __hip_bfloat16* __restrict__ wdst)
{
    int t = blockIdx.x * 256 + threadIdx.x;
    if (t >= 9 * 64 * 64) return;
    int r = t >> 12, co = (t >> 6) & 63, ci = t & 63;
    wdst[t] = __float2bfloat16(wsrc[(co * 64 + ci) * 9 + r]);
}

// ---------------- 2) depthwise conv q,k + unfold, coalesced stores ----------
__global__ __launch_bounds__(256) void conv_qk_unfold2(
    const float* __restrict__ x,
    const float* __restrict__ wq, const float* __restrict__ bq,
    const float* __restrict__ wk, const float* __restrict__ bk,
    __hip_bfloat16* __restrict__ Q, __hip_bfloat16* __restrict__ K)
{
    int py  = blockIdx.x;          // 0..7
    int oc8 = blockIdx.y;          // 0..7
    int f   = blockIdx.z;          // 0..111
    int t = threadIdx.x;
    int w = t >> 6, lane = t & 63;
    int cg = lane >> 3, ky = lane & 7;
    int c  = oc8 * 8 + cg;
    int yy = py * 8 + ky;
    const float* xp = x + ((size_t)f * C_ + c) * (H_ * W_);
    float wqr[9], wkr[9];
    #pragma unroll
    for (int i = 0; i < 9; ++i) { wqr[i] = wq[c * 9 + i]; wkr[i] = wk[c * 9 + i]; }
    float bqv = bq[c], bkv = bk[c];
    int b = f / T_, tt = f % T_;
    unsigned short* Qp = (unsigned short*)Q;
    unsigned short* Kp = (unsigned short*)K;

    #pragma unroll
    for (int pi = 0; pi < 2; ++pi) {
        int px = w + pi * 4;
        int xb = px * 8;
        float acq[8], ack[8];
        #pragma unroll
        for (int j = 0; j < 8; ++j) { acq[j] = bqv; ack[j] = bkv; }
        #pragma unroll
        for (int dy = 0; dy < 3; ++dy) {
            int Y = yy + dy - 1;
            if ((unsigned)Y >= (unsigned)H_) continue;
            const float* rp = xp + Y * W_ + xb;
            float r[10];
            r[0] = (xb > 0) ? rp[-1] : 0.f;
            #pragma unroll
            for (int j = 0; j < 8; ++j) r[j + 1] = rp[j];
            r[9] = (xb < 56) ? rp[8] : 0.f;
            float w0q = wqr[dy * 3], w1q = wqr[dy * 3 + 1], w2q = wqr[dy * 3 + 2];
            float w0k = wkr[dy * 3], w1k = wkr[dy * 3 + 1], w2k = wkr[dy * 3 + 2];
            #pragma unroll
            for (int j = 0; j < 8; ++j) {
                acq[j] += w0q * r[j] + w1q * r[j + 1] + w2q * r[j + 2];
                ack[j] += w0k * r[j] + w1k * r[j + 1] + w2k * r[j + 2];
            }
        }
        int s = tt * 64 + py * 8 + px;
        size_t off = ((size_t)b * S_ + s) * D_ + (size_t)c * 64 + ky * 8;
        unsigned short pq[8], pk[8];
        #pragma unroll
        for (int j = 0; j < 8; ++j) { pq[j] = f2bf(acq[j]); pk[j] = f2bf(ack[j]); }
        *(short8v*)(Qp + off) = *(const short8v*)pq;
        *(short8v*)(Kp + off) = *(const short8v*)pk;
    }
}

// ---------------- 3/7) dense 3x3 conv: implicit-GEMM MFMA, Wt in LDS --------
// Block: frame x 8-row band. 4 waves; wave w owns output rows y0+2w, y0+2w+1.
// Per wave: M=128 (2 rows x 64 x) x N=64 (co), K=576. A=x-frag, B=W-frag so
// C/D col=co, row=x -> coalesced stores. LDS: xs[10][66][128B] + wl[3][64][128B].
template<bool IS_V>
__global__ __launch_bounds__(256, 1) void conv_mfma2(
    const void* __restrict__ src,                 // IS_V: f32 x ; else bf16 FEAT
    const __hip_bfloat16* __restrict__ Wt,        // [9][64][64] bf16
    const float* __restrict__ bias,
    const float* __restrict__ xin,                // residual input (conv_c)
    void* __restrict__ dst)                       // IS_V: bf16 V ; else f32 out
{
    __shared__ char xs[10 * 66 * 128];            // 84480 B
    __shared__ char wl[3 * 64 * 128];             // 24576 B
    const int f    = blockIdx.y;
    const int band = blockIdx.x;                  // 0..7
    const int y0   = band * 8;
    const int tid  = threadIdx.x;
    const int lane = tid & 63;
    const int w    = tid >> 6;
    const int q    = lane >> 4;
    const int l15  = lane & 15;

    // ---- stage xs: input rows y0-1 .. y0+8
    for (int e = tid; e < 10 * 16 * 64; e += 256) {
        int x  = e & 63;
        int cg = (e >> 6) & 15;
        int r  = e >> 10;
        int y  = y0 - 1 + r;
        unsigned short p[4];
        if ((unsigned)y < (unsigned)H_) {
            #pragma unroll
            for (int j = 0; j < 4; ++j) {
                size_t gi = (((size_t)f * C_ + cg * 4 + j) * H_ + y) * W_ + x;
                if constexpr (IS_V) p[j] = f2bf(((const float*)src)[gi]);
                else                p[j] = ((const unsigned short*)src)[gi];
            }
        } else { p[0] = p[1] = p[2] = p[3] = 0; }
        int xp = x + 1;
        int byte = (r * 66 + xp) * 128 + ((cg * 8) ^ ((xp & 7) << 4));
        *(uint2*)(xs + byte) = *(uint2*)p;
    }
    for (int e = tid; e < 10 * 16 * 2; e += 256) {
        int side = e & 1;
        int cg   = (e >> 1) & 15;
        int r    = e >> 5;
        int xp   = side ? 65 : 0;
        int byte = (r * 66 + xp) * 128 + ((cg * 8) ^ ((xp & 7) << 4));
        *(uint2*)(xs + byte) = uint2{0u, 0u};
    }

    float4v acc[2][4][4] = {};
    const unsigned short* Wg = (const unsigned short*)Wt;

    for (int ky = 0; ky < 3; ++ky) {
        __syncthreads();                          // protect wl from prev readers
        for (int i = tid; i < 1536; i += 256) {   // stage Wt slice (3 kx)
            int kx  = i >> 9;
            int rem = i & 511;
            int row = rem >> 3;
            int c8  = (rem & 7) * 8;
            short8v v = *(const short8v*)(Wg + ((ky * 3 + kx) * 4096 + row * 64 + c8));
            *(short8v*)(wl + kx * 8192 + row * 128 + ((c8 * 2) ^ ((row & 7) << 4))) = v;
        }
        __syncthreads();
        #pragma unroll
        for (int kx = 0; kx < 3; ++kx) {
            #pragma unroll
            for (int kc = 0; kc < 2; ++kc) {
                int kB = kc * 64 + q * 16;
                short8v bfr[4];
                #pragma unroll
                for (int nt = 0; nt < 4; ++nt)
                    bfr[nt] = frag_ld(wl + kx * 8192, nt * 16 + l15, kB);
                #pragma unroll
                for (int rs = 0; rs < 2; ++rs) {
                    int ri = 2 * w + ky + rs;     // xs row slot
                    #pragma unroll
                    for (int xt = 0; xt < 4; ++xt) {
                        int xp = xt * 16 + l15 + kx;
                        short8v av = *(const short8v*)(xs + (ri * 66 + xp) * 128 +
                                                       (kB ^ ((xp & 7) << 4)));
                        #pragma unroll
                        for (int nt = 0; nt < 4; ++nt)
                            acc[rs][xt][nt] = __builtin_amdgcn_mfma_f32_16x16x32_bf16(
                                av, bfr[nt], acc[rs][xt][nt], 0, 0, 0);
                    }
                }
            }
        }
    }

    // ---- epilogue: D col(l15)=co, row(q*4+j)=x
    float bco[4];
    #pragma unroll
    for (int nt = 0; nt < 4; ++nt) bco[nt] = bias[nt * 16 + l15];
    const int bb = f / T_, tt = f % T_;
    #pragma unroll
    for (int rs = 0; rs < 2; ++rs) {
        int R = y0 + 2 * w + rs;
        #pragma unroll
        for (int xt = 0; xt < 4; ++xt) {
            #pragma unroll
            for (int nt = 0; nt < 4; ++nt) {
                int co = nt * 16 + l15;
                if constexpr (IS_V) {
                    int s  = tt * 64 + band * 8 + xt * 2 + (q >> 1);
                    int d0 = co * 64 + (R & 7) * 8 + (q & 1) * 4;
                    unsigned short pk[4];
                    #pragma unroll
                    for (int j = 0; j < 4; ++j)
                        pk[j] = f2bf(acc[rs][xt][nt][j] + bco[nt]);
                    *(uint2*)((unsigned short*)dst + ((size_t)bb * S_ + s) * D_ + d0) =
                        *(const uint2*)pk;
                } else {
                    size_t o = (((size_t)f * C_ + co) * H_ + R) * W_ + xt * 16 + q * 4;
                    float4 rv = *(const float4*)(xin + o);
                    float4 ov;
                    ov.x = acc[rs][xt][nt][0] + bco[nt] + rv.x;
                    ov.y = acc[rs][xt][nt][1] + bco[nt] + rv.y;
                    ov.z = acc[rs][xt][nt][2] + bco[nt] + rv.z;
                    ov.w = acc[rs][xt][nt][3] + bco[nt] + rv.w;
                    *(float4*)((float*)dst + o) = ov;
                }
            }
        }
    }
}

// ---------------- 4) ATTN = (1/64) Q K^T via MFMA ---------------------------
__global__ __launch_bounds__(512, 2) void gemm_qk_mfma(
    const __hip_bfloat16* __restrict__ Qg,
    const __hip_bfloat16* __restrict__ Kg,
    float* __restrict__ ATTN)
{
    __shared__ alignas(16) char lds[32768];
    char* ldsA = lds;
    char* ldsB = lds + 16384;
    int bid = blockIdx.x;
    int lb  = (bid & 7) * 32 + (bid >> 3);
    int bb  = lb >> 4;
    int m0  = ((lb >> 2) & 3) * 128;
    int n0  = (lb & 3) * 128;
    const unsigned short* Ag = (const unsigned short*)Qg + (size_t)bb * S_ * D_ + (size_t)m0 * D_;
    const unsigned short* Bg = (const unsigned short*)Kg + (size_t)bb * S_ * D_ + (size_t)n0 * D_;
    int t = threadIdx.x;
    int w = t >> 6, l = t & 63, q = l >> 4, l15 = l & 15;
    int wm = w >> 2, wn = w & 3;
    int r0 = t >> 3, c0 = (t & 7) * 8;
    int r1 = 64 + r0;
    short8v sA0, sA1, sB0, sB1;
    sA0 = *(const short8v*)(Ag + (size_t)r0 * D_ + c0);
    sA1 = *(const short8v*)(Ag + (size_t)r1 * D_ + c0);
    sB0 = *(const short8v*)(Bg + (size_t)r0 * D_ + c0);
    sB1 = *(const short8v*)(Bg + (size_t)r1 * D_ + c0);

    float4v acc[4][2] = {};
    int swz0 = (c0 * 2) ^ ((r0 & 7) << 4);
    for (int k0 = 0; k0 < D_; k0 += 64) {
        __syncthreads();
        *(short8v*)(ldsA + r0 * 128 + swz0) = sA0;
        *(short8v*)(ldsA + r1 * 128 + swz0) = sA1;
        *(short8v*)(ldsB + r0 * 128 + swz0) = sB0;
        *(short8v*)(ldsB + r1 * 128 + swz0) = sB1;
        if (k0 + 64 < D_) {
            int kn = k0 + 64;
            sA0 = *(const short8v*)(Ag + (size_t)r0 * D_ + kn + c0);
            sA1 = *(const short8v*)(Ag + (size_t)r1 * D_ + kn + c0);
            sB0 = *(const short8v*)(Bg + (size_t)r0 * D_ + kn + c0);
            sB1 = *(const short8v*)(Bg + (size_t)r1 * D_ + kn + c0);
        }
        __syncthreads();
        #pragma unroll
        for (int kc = 0; kc < 2; ++kc) {
            int kB = kc * 64 + q * 16;
            short8v a[4], b[2];
            #pragma unroll
            for (int mt = 0; mt < 4; ++mt) a[mt] = frag_ld(ldsA, wm * 64 + mt * 16 + l15, kB);
            #pragma unroll
            for (int nt = 0; nt < 2; ++nt) b[nt] = frag_ld(ldsB, wn * 32 + nt * 16 + l15, kB);
            #pragma unroll
            for (int mt = 0; mt < 4; ++mt)
                #pragma unroll
                for (int nt = 0; nt < 2; ++nt)
                    acc[mt][nt] = __builtin_amdgcn_mfma_f32_16x16x32_bf16(
                        a[mt], b[nt], acc[mt][nt], 0, 0, 0);
        }
    }
    const float scale = 1.0f / 64.0f;
    #pragma unroll
    for (int mt = 0; mt < 4; ++mt) {
        #pragma unroll
        for (int nt = 0; nt < 2; ++nt) {
            int u = n0 + wn * 32 + nt * 16 + l15;
            #pragma unroll
            for (int j = 0; j < 4; ++j) {
                int s = m0 + wm * 64 + mt * 16 + q * 4 + j;
                if (s < S_ && u < S_)
                    ATTN[((size_t)bb * S_ + s) * S_ + u] = acc[mt][nt][j] * scale;
            }
        }
    }
}

// ---------------- 5) row softmax -> bf16 P ----------------------------------
__global__ __launch_bounds__(64) void softmax_rows(const float* __restrict__ ATTN,
                                                   unsigned short* __restrict__ P)
{
    size_t row = blockIdx.x;
    const float* p = ATTN + row * S_;
    int lane = threadIdx.x;
    float vals[7];
    float m = -1e30f;
    #pragma unroll
    for (int i = 0; i < 7; ++i) { vals[i] = p[lane + i * 64]; m = fmaxf(m, vals[i]); }
    #pragma unroll
    for (int off = 32; off; off >>= 1) m = fmaxf(m, __shfl_xor(m, off));
    float sum = 0.f;
    #pragma unroll
    for (int i = 0; i < 7; ++i) { vals[i] = __expf(vals[i] - m); sum += vals[i]; }
    #pragma unroll
    for (int off = 32; off; off >>= 1) sum += __shfl_xor(sum, off);
    float inv = 1.f / sum;
    #pragma unroll
    for (int i = 0; i < 7; ++i) P[row * S_ + lane + i * 64] = f2bf(vals[i] * inv);
}

// ---------------- 6) FEAT = P @ V via MFMA (V transposed in LDS) ------------
__global__ __launch_bounds__(256, 2) void gemm_pv_mfma(
    const unsigned short* __restrict__ Pg,
    const __hip_bfloat16* __restrict__ Vg,
    __hip_bfloat16* __restrict__ FEAT)
{
    __shared__ alignas(16) char lds[32768];
    char* ldsA = lds;
    char* ldsB = lds + 16384;
    int bid = blockIdx.x;
    int lb  = (bid & 7) * 256 + (bid >> 3);
    int bb  = lb >> 7;
    int tl  = lb & 127;
    int m0  = (tl >> 5) * 128;
    int n0  = (tl & 31) * 128;
    const unsigned short* Ag = Pg + (size_t)bb * S_ * S_ + (size_t)m0 * S_;
    const unsigned short* Bg = (const unsigned short*)Vg + (size_t)bb * S_ * D_ + n0;
    int t = threadIdx.x;
    int w = t >> 6, l = t & 63, q = l >> 4, l15 = l & 15;
    int wm = w >> 1, wn = w & 1;
    float4v acc[4][4] = {};
    for (int k0 = 0; k0 < S_; k0 += 64) {
        __syncthreads();
        stage_tile<256>(ldsA, Ag + k0, S_, t);
        stage_vt(ldsB, Bg + (size_t)k0 * D_, t);
        __syncthreads();
        #pragma unroll
        for (int kc = 0; kc < 2; ++kc) {
            int kB = kc * 64 + q * 16;
            short8v a[4], b[4];
            #pragma unroll
            for (int mt = 0; mt < 4; ++mt) a[mt] = frag_ld(ldsA, wm * 64 + mt * 16 + l15, kB);
            #pragma unroll
            for (int nt = 0; nt < 4; ++nt) b[nt] = frag_ld(ldsB, wn * 64 + nt * 16 + l15, kB);
            #pragma unroll
            for (int mt = 0; mt < 4; ++mt)
                #pragma unroll
                for (int nt = 0; nt < 4; ++nt)
                    acc[mt][nt] = __builtin_amdgcn_mfma_f32_16x16x32_bf16(
                        a[mt], b[nt], acc[mt][nt], 0, 0, 0);
        }
    }
    #pragma unroll
    for (int mt = 0; mt < 4; ++mt) {
        #pragma unroll
        for (int j = 0; j < 4; ++j) {
            int s = m0 + wm * 64 + mt * 16 + q * 4 + j;
            if (s >= S_) continue;
            int f  = bb * T_ + (s >> 6);
            int l6 = s & 63;
            #pragma unroll
            for (int nt = 0; nt < 4; ++nt) {
                int d = n0 + wn * 64 + nt * 16 + l15;
                int c = d >> 6, r = d & 63;
                int y  = ((l6 >> 3) << 3) + (r >> 3);
                int xx = ((l6 & 7) << 3) + (r & 7);
                FEAT[(((size_t)f * C_ + c) * H_ + y) * W_ + xx] =
                    __float2bfloat16(acc[mt][nt][j]);
            }
        }
    }
}

// ---------------------------------------------------------------------------
extern "C" void kernel_launch(void* const* d_in, const int* in_sizes, int n_in,
                              void* d_out, int out_size, void* d_ws, size_t ws_size,
                              hipStream_t stream)
{
    const float* x  = (const float*)d_in[0];
    const float* wq = (const float*)d_in[1];
    const float* bq = (const float*)d_in[2];
    const float* wk = (const float*)d_in[3];
    const float* bk = (const float*)d_in[4];
    const float* wv = (const float*)d_in[5];
    const float* bv = (const float*)d_in[6];
    const float* wc = (const float*)d_in[7];
    const float* bc = (const float*)d_in[8];
    float* out = (float*)d_out;

    __hip_bfloat16* Qb = (__hip_bfloat16*)d_ws;
    __hip_bfloat16* Kb = Qb + QKV_E;
    __hip_bfloat16* Vb = Kb + QKV_E;
    float* ATTN = (float*)(Vb + QKV_E);
    __hip_bfloat16* Wt_v = (__hip_bfloat16*)(ATTN + ATTN_E);
    __hip_bfloat16* Wt_c = Wt_v + 9 * 64 * 64;
    unsigned short* Pb   = (unsigned short*)Kb;   // aliases Kb (dead after qk)
    __hip_bfloat16* FEAT = Qb;                    // aliases Qb (dead after qk)

    prep_w<<<144, 256, 0, stream>>>(wv, Wt_v);
    prep_w<<<144, 256, 0, stream>>>(wc, Wt_c);

    conv_qk_unfold2<<<dim3(8, 8, NFR), 256, 0, stream>>>(x, wq, bq, wk, bk, Qb, Kb);
    conv_mfma2<true><<<dim3(8, NFR), 256, 0, stream>>>(x, Wt_v, bv, nullptr, Vb);
    gemm_qk_mfma<<<256, 512, 0, stream>>>(Qb, Kb, ATTN);
    softmax_rows<<<B_ * S_, 64, 0, stream>>>(ATTN, Pb);
    gemm_pv_mfma<<<2048, 256, 0, stream>>>(Pb, Vb, FEAT);
    conv_mfma2<false><<<dim3(8, NFR), 256, 0, stream>>>(FEAT, Wt_c, bc, x, out);
}

// Round 6
// 459.897 us; speedup vs baseline: 15.3569x; 1.1793x over previous
//
#include <hip/hip_runtime.h>
#include <hip/hip_bf16.h>

// ---------------------------------------------------------------------------
// globalAttention: b=16 t=7 c=64 h=w=64, P=8  ->  112 frames, S=448, D=4096
//   1) prep_w x2      : wv,wc fp32 [co][ci][3][3] -> bf16 Wt[r][co][ci]
//   2) conv_qk_unfold2: depthwise 3x3 conv (q,k) -> bf16 Q,K, 1KB wave stores
//   3) conv_mfma2<V>  : dense conv v, MFMA implicit GEMM, Wt staged in LDS,
//                       4-row bands, 1 row/wave (M=64x N=64co K=576),
//                       75.3KB LDS -> 2 blocks/CU (occupancy lever, r5)
//   4) gemm_qk_mfma   : ATTN = (1/64) Q K^T   (bf16 MFMA, fp32 out)
//   5) softmax_rows   : row softmax -> bf16 P  (P aliases Kb)
//   6) gemm_pv_mfma   : FEAT[f][c][y][x] bf16 = P @ V   (V transposed in LDS)
//   7) conv_mfma2<C>  : dense conv c + bias + residual -> d_out (float4 stores)
// Workspace: Qb[58.7M] Kb[58.7M] Vb[58.7M] ATTN[12.8M] Wt[144K]
// P(bf16) aliases Kb; FEAT(bf16) aliases Qb. Total ~189.5 MiB.
// ---------------------------------------------------------------------------

namespace {
constexpr int NFR = 112;
constexpr int T_  = 7;
constexpr int B_  = 16;
constexpr int C_  = 64;
constexpr int H_  = 64;
constexpr int W_  = 64;
constexpr int S_  = 448;
constexpr int D_  = 4096;
constexpr size_t QKV_E = (size_t)B_ * S_ * D_;
constexpr size_t ATTN_E = (size_t)B_ * S_ * S_;
}

typedef __attribute__((ext_vector_type(8))) short short8v;
typedef __attribute__((ext_vector_type(4))) float float4v;

__device__ __forceinline__ float bfu2f(unsigned short u) {
    union { unsigned int i; float f; } v; v.i = ((unsigned int)u) << 16; return v.f;
}
__device__ __forceinline__ unsigned short f2bf(float f) {
    __hip_bfloat16 h = __float2bfloat16(f);
    return *reinterpret_cast<unsigned short*>(&h);
}

// element (r, k) of a Rx64-short tile lives at byte r*128 + ((2k)^((r&7)<<4))
__device__ __forceinline__ short8v frag_ld(const char* ldsb, int r, int kByte) {
    return *(const short8v*)(ldsb + r * 128 + (kByte ^ ((r & 7) << 4)));
}

// stage 128 rows x 64 shorts from g (row stride ldg shorts) into swizzled LDS
template<int NTHR>
__device__ __forceinline__ void stage_tile(char* ldsb, const unsigned short* g,
                                           int ldg, int t) {
    #pragma unroll
    for (int i = 0; i < 1024 / NTHR; ++i) {
        int e = i * NTHR + t;
        int r = e >> 3, c8 = (e & 7) * 8;
        short8v v = *(const short8v*)(g + (size_t)r * ldg + c8);
        *(short8v*)(ldsb + r * 128 + ((c8 * 2) ^ ((r & 7) << 4))) = v;
    }
}

// stage V[u][d] tile (64 u x 128 d) TRANSPOSED into LDS as [d][u] swizzled
__device__ __forceinline__ void stage_vt(char* ldsb, const unsigned short* g, int t) {
    int d0 = (t & 15) * 8;
    int u0 = (t >> 4) * 4;
    short8v r0 = *(const short8v*)(g + (size_t)(u0 + 0) * D_ + d0);
    short8v r1 = *(const short8v*)(g + (size_t)(u0 + 1) * D_ + d0);
    short8v r2 = *(const short8v*)(g + (size_t)(u0 + 2) * D_ + d0);
    short8v r3 = *(const short8v*)(g + (size_t)(u0 + 3) * D_ + d0);
    #pragma unroll
    for (int j = 0; j < 8; ++j) {
        unsigned int lo = (unsigned short)r0[j] | (((unsigned int)(unsigned short)r1[j]) << 16);
        unsigned int hi = (unsigned short)r2[j] | (((unsigned int)(unsigned short)r3[j]) << 16);
        int d = d0 + j;
        int byte = d * 128 + (((unsigned)(u0 * 2)) ^ ((d & 7) << 4));
        *(uint2*)(ldsb + byte) = uint2{lo, hi};
    }
}

// ---------------- 1) weight transpose: [co][ci][3][3] f32 -> [r][co][ci] bf16
__global__ __launch_bounds__(256) void prep_w(const float* __restrict__ wsrc,
                                              __hip_bfloat16* __restrict__ wdst)
{
    int t = blockIdx.x * 256 + threadIdx.x;
    if (t >= 9 * 64 * 64) return;
    int r = t >> 12, co = (t >> 6) & 63, ci = t & 63;
    wdst[t] = __float2bfloat16(wsrc[(co * 64 + ci) * 9 + r]);
}

// ---------------- 2) depthwise conv q,k + unfold, coalesced stores ----------
__global__ __launch_bounds__(256) void conv_qk_unfold2(
    const float* __restrict__ x,
    const float* __restrict__ wq, const float* __restrict__ bq,
    const float* __restrict__ wk, const float* __restrict__ bk,
    __hip_bfloat16* __restrict__ Q, __hip_bfloat16* __restrict__ K)
{
    int py  = blockIdx.x;          // 0..7
    int oc8 = blockIdx.y;          // 0..7
    int f   = blockIdx.z;          // 0..111
    int t = threadIdx.x;
    int w = t >> 6, lane = t & 63;
    int cg = lane >> 3, ky = lane & 7;
    int c  = oc8 * 8 + cg;
    int yy = py * 8 + ky;
    const float* xp = x + ((size_t)f * C_ + c) * (H_ * W_);
    float wqr[9], wkr[9];
    #pragma unroll
    for (int i = 0; i < 9; ++i) { wqr[i] = wq[c * 9 + i]; wkr[i] = wk[c * 9 + i]; }
    float bqv = bq[c], bkv = bk[c];
    int b = f / T_, tt = f % T_;
    unsigned short* Qp = (unsigned short*)Q;
    unsigned short* Kp = (unsigned short*)K;

    #pragma unroll
    for (int pi = 0; pi < 2; ++pi) {
        int px = w + pi * 4;
        int xb = px * 8;
        float acq[8], ack[8];
        #pragma unroll
        for (int j = 0; j < 8; ++j) { acq[j] = bqv; ack[j] = bkv; }
        #pragma unroll
        for (int dy = 0; dy < 3; ++dy) {
            int Y = yy + dy - 1;
            if ((unsigned)Y >= (unsigned)H_) continue;
            const float* rp = xp + Y * W_ + xb;
            float r[10];
            r[0] = (xb > 0) ? rp[-1] : 0.f;
            #pragma unroll
            for (int j = 0; j < 8; ++j) r[j + 1] = rp[j];
            r[9] = (xb < 56) ? rp[8] : 0.f;
            float w0q = wqr[dy * 3], w1q = wqr[dy * 3 + 1], w2q = wqr[dy * 3 + 2];
            float w0k = wkr[dy * 3], w1k = wkr[dy * 3 + 1], w2k = wkr[dy * 3 + 2];
            #pragma unroll
            for (int j = 0; j < 8; ++j) {
                acq[j] += w0q * r[j] + w1q * r[j + 1] + w2q * r[j + 2];
                ack[j] += w0k * r[j] + w1k * r[j + 1] + w2k * r[j + 2];
            }
        }
        int s = tt * 64 + py * 8 + px;
        size_t off = ((size_t)b * S_ + s) * D_ + (size_t)c * 64 + ky * 8;
        unsigned short pq[8], pk[8];
        #pragma unroll
        for (int j = 0; j < 8; ++j) { pq[j] = f2bf(acq[j]); pk[j] = f2bf(ack[j]); }
        *(short8v*)(Qp + off) = *(const short8v*)pq;
        *(short8v*)(Kp + off) = *(const short8v*)pk;
    }
}

// ---------------- 3/7) dense 3x3 conv: implicit-GEMM MFMA, Wt in LDS --------
// Block: frame x 4-row band. 4 waves; wave w owns output row y0+w.
// Per wave: M=64 (x) x N=64 (co), K=576. A=x-frag, B=W-frag so C/D col=co,
// row=x -> coalesced stores. LDS: xs[6][66][128B] + wl[3][64][128B] = 75.3KB
// -> 2 blocks/CU (8 waves/CU); grid 16x112 = 7 blocks/CU exact.
template<bool IS_V>
__global__ __launch_bounds__(256, 2) void conv_mfma2(
    const void* __restrict__ src,                 // IS_V: f32 x ; else bf16 FEAT
    const __hip_bfloat16* __restrict__ Wt,        // [9][64][64] bf16
    const float* __restrict__ bias,
    const float* __restrict__ xin,                // residual input (conv_c)
    void* __restrict__ dst)                       // IS_V: bf16 V ; else f32 out
{
    __shared__ char xs[6 * 66 * 128];             // 50688 B
    __shared__ char wl[3 * 64 * 128];             // 24576 B
    const int f    = blockIdx.y;
    const int band = blockIdx.x;                  // 0..15
    const int y0   = band * 4;
    const int tid  = threadIdx.x;
    const int lane = tid & 63;
    const int w    = tid >> 6;
    const int q    = lane >> 4;
    const int l15  = lane & 15;

    // ---- stage xs: input rows y0-1 .. y0+4
    for (int e = tid; e < 6 * 16 * 64; e += 256) {
        int x  = e & 63;
        int cg = (e >> 6) & 15;
        int r  = e >> 10;
        int y  = y0 - 1 + r;
        unsigned short p[4];
        if ((unsigned)y < (unsigned)H_) {
            #pragma unroll
            for (int j = 0; j < 4; ++j) {
                size_t gi = (((size_t)f * C_ + cg * 4 + j) * H_ + y) * W_ + x;
                if constexpr (IS_V) p[j] = f2bf(((const float*)src)[gi]);
                else                p[j] = ((const unsigned short*)src)[gi];
            }
        } else { p[0] = p[1] = p[2] = p[3] = 0; }
        int xp = x + 1;
        int byte = (r * 66 + xp) * 128 + ((cg * 8) ^ ((xp & 7) << 4));
        *(uint2*)(xs + byte) = *(uint2*)p;
    }
    for (int e = tid; e < 6 * 16 * 2; e += 256) {
        int side = e & 1;
        int cg   = (e >> 1) & 15;
        int r    = e >> 5;
        int xp   = side ? 65 : 0;
        int byte = (r * 66 + xp) * 128 + ((cg * 8) ^ ((xp & 7) << 4));
        *(uint2*)(xs + byte) = uint2{0u, 0u};
    }

    float4v acc[4][4] = {};
    const unsigned short* Wg = (const unsigned short*)Wt;

    for (int ky = 0; ky < 3; ++ky) {
        __syncthreads();                          // protect wl from prev readers
        for (int i = tid; i < 1536; i += 256) {   // stage Wt slice (3 kx)
            int kx  = i >> 9;
            int rem = i & 511;
            int row = rem >> 3;
            int c8  = (rem & 7) * 8;
            short8v v = *(const short8v*)(Wg + ((ky * 3 + kx) * 4096 + row * 64 + c8));
            *(short8v*)(wl + kx * 8192 + row * 128 + ((c8 * 2) ^ ((row & 7) << 4))) = v;
        }
        __syncthreads();
        const int ri = w + ky;                    // xs row slot for this wave
        #pragma unroll
        for (int kx = 0; kx < 3; ++kx) {
            #pragma unroll
            for (int kc = 0; kc < 2; ++kc) {
                int kB = kc * 64 + q * 16;
                short8v bfr[4];
                #pragma unroll
                for (int nt = 0; nt < 4; ++nt)
                    bfr[nt] = frag_ld(wl + kx * 8192, nt * 16 + l15, kB);
                #pragma unroll
                for (int xt = 0; xt < 4; ++xt) {
                    int xp = xt * 16 + l15 + kx;
                    short8v av = *(const short8v*)(xs + (ri * 66 + xp) * 128 +
                                                   (kB ^ ((xp & 7) << 4)));
                    #pragma unroll
                    for (int nt = 0; nt < 4; ++nt)
                        acc[xt][nt] = __builtin_amdgcn_mfma_f32_16x16x32_bf16(
                            av, bfr[nt], acc[xt][nt], 0, 0, 0);
                }
            }
        }
    }

    // ---- epilogue: D col(l15)=co, row(q*4+j)=x
    float bco[4];
    #pragma unroll
    for (int nt = 0; nt < 4; ++nt) bco[nt] = bias[nt * 16 + l15];
    const int bb = f / T_, tt = f % T_;
    const int R = y0 + w;
    #pragma unroll
    for (int xt = 0; xt < 4; ++xt) {
        #pragma unroll
        for (int nt = 0; nt < 4; ++nt) {
            int co = nt * 16 + l15;
            if constexpr (IS_V) {
                int s  = tt * 64 + (R >> 3) * 8 + xt * 2 + (q >> 1);
                int d0 = co * 64 + (R & 7) * 8 + (q & 1) * 4;
                unsigned short pk[4];
                #pragma unroll
                for (int j = 0; j < 4; ++j)
                    pk[j] = f2bf(acc[xt][nt][j] + bco[nt]);
                *(uint2*)((unsigned short*)dst + ((size_t)bb * S_ + s) * D_ + d0) =
                    *(const uint2*)pk;
            } else {
                size_t o = (((size_t)f * C_ + co) * H_ + R) * W_ + xt * 16 + q * 4;
                float4 rv = *(const float4*)(xin + o);
                float4 ov;
                ov.x = acc[xt][nt][0] + bco[nt] + rv.x;
                ov.y = acc[xt][nt][1] + bco[nt] + rv.y;
                ov.z = acc[xt][nt][2] + bco[nt] + rv.z;
                ov.w = acc[xt][nt][3] + bco[nt] + rv.w;
                *(float4*)((float*)dst + o) = ov;
            }
        }
    }
}

// ---------------- 4) ATTN = (1/64) Q K^T via MFMA ---------------------------
__global__ __launch_bounds__(512, 2) void gemm_qk_mfma(
    const __hip_bfloat16* __restrict__ Qg,
    const __hip_bfloat16* __restrict__ Kg,
    float* __restrict__ ATTN)
{
    __shared__ alignas(16) char lds[32768];
    char* ldsA = lds;
    char* ldsB = lds + 16384;
    int bid = blockIdx.x;
    int lb  = (bid & 7) * 32 + (bid >> 3);
    int bb  = lb >> 4;
    int m0  = ((lb >> 2) & 3) * 128;
    int n0  = (lb & 3) * 128;
    const unsigned short* Ag = (const unsigned short*)Qg + (size_t)bb * S_ * D_ + (size_t)m0 * D_;
    const unsigned short* Bg = (const unsigned short*)Kg + (size_t)bb * S_ * D_ + (size_t)n0 * D_;
    int t = threadIdx.x;
    int w = t >> 6, l = t & 63, q = l >> 4, l15 = l & 15;
    int wm = w >> 2, wn = w & 3;
    int r0 = t >> 3, c0 = (t & 7) * 8;
    int r1 = 64 + r0;
    short8v sA0, sA1, sB0, sB1;
    sA0 = *(const short8v*)(Ag + (size_t)r0 * D_ + c0);
    sA1 = *(const short8v*)(Ag + (size_t)r1 * D_ + c0);
    sB0 = *(const short8v*)(Bg + (size_t)r0 * D_ + c0);
    sB1 = *(const short8v*)(Bg + (size_t)r1 * D_ + c0);

    float4v acc[4][2] = {};
    int swz0 = (c0 * 2) ^ ((r0 & 7) << 4);
    for (int k0 = 0; k0 < D_; k0 += 64) {
        __syncthreads();
        *(short8v*)(ldsA + r0 * 128 + swz0) = sA0;
        *(short8v*)(ldsA + r1 * 128 + swz0) = sA1;
        *(short8v*)(ldsB + r0 * 128 + swz0) = sB0;
        *(short8v*)(ldsB + r1 * 128 + swz0) = sB1;
        if (k0 + 64 < D_) {
            int kn = k0 + 64;
            sA0 = *(const short8v*)(Ag + (size_t)r0 * D_ + kn + c0);
            sA1 = *(const short8v*)(Ag + (size_t)r1 * D_ + kn + c0);
            sB0 = *(const short8v*)(Bg + (size_t)r0 * D_ + kn + c0);
            sB1 = *(const short8v*)(Bg + (size_t)r1 * D_ + kn + c0);
        }
        __syncthreads();
        #pragma unroll
        for (int kc = 0; kc < 2; ++kc) {
            int kB = kc * 64 + q * 16;
            short8v a[4], b[2];
            #pragma unroll
            for (int mt = 0; mt < 4; ++mt) a[mt] = frag_ld(ldsA, wm * 64 + mt * 16 + l15, kB);
            #pragma unroll
            for (int nt = 0; nt < 2; ++nt) b[nt] = frag_ld(ldsB, wn * 32 + nt * 16 + l15, kB);
            #pragma unroll
            for (int mt = 0; mt < 4; ++mt)
                #pragma unroll
                for (int nt = 0; nt < 2; ++nt)
                    acc[mt][nt] = __builtin_amdgcn_mfma_f32_16x16x32_bf16(
                        a[mt], b[nt], acc[mt][nt], 0, 0, 0);
        }
    }
    const float scale = 1.0f / 64.0f;
    #pragma unroll
    for (int mt = 0; mt < 4; ++mt) {
        #pragma unroll
        for (int nt = 0; nt < 2; ++nt) {
            int u = n0 + wn * 32 + nt * 16 + l15;
            #pragma unroll
            for (int j = 0; j < 4; ++j) {
                int s = m0 + wm * 64 + mt * 16 + q * 4 + j;
                if (s < S_ && u < S_)
                    ATTN[((size_t)bb * S_ + s) * S_ + u] = acc[mt][nt][j] * scale;
            }
        }
    }
}

// ---------------- 5) row softmax -> bf16 P ----------------------------------
__global__ __launch_bounds__(64) void softmax_rows(const float* __restrict__ ATTN,
                                                   unsigned short* __restrict__ P)
{
    size_t row = blockIdx.x;
    const float* p = ATTN + row * S_;
    int lane = threadIdx.x;
    float vals[7];
    float m = -1e30f;
    #pragma unroll
    for (int i = 0; i < 7; ++i) { vals[i] = p[lane + i * 64]; m = fmaxf(m, vals[i]); }
    #pragma unroll
    for (int off = 32; off; off >>= 1) m = fmaxf(m, __shfl_xor(m, off));
    float sum = 0.f;
    #pragma unroll
    for (int i = 0; i < 7; ++i) { vals[i] = __expf(vals[i] - m); sum += vals[i]; }
    #pragma unroll
    for (int off = 32; off; off >>= 1) sum += __shfl_xor(sum, off);
    float inv = 1.f / sum;
    #pragma unroll
    for (int i = 0; i < 7; ++i) P[row * S_ + lane + i * 64] = f2bf(vals[i] * inv);
}

// ---------------- 6) FEAT = P @ V via MFMA (V transposed in LDS) ------------
__global__ __launch_bounds__(256, 2) void gemm_pv_mfma(
    const unsigned short* __restrict__ Pg,
    const __hip_bfloat16* __restrict__ Vg,
    __hip_bfloat16* __restrict__ FEAT)
{
    __shared__ alignas(16) char lds[32768];
    char* ldsA = lds;
    char* ldsB = lds + 16384;
    int bid = blockIdx.x;
    int lb  = (bid & 7) * 256 + (bid >> 3);
    int bb  = lb >> 7;
    int tl  = lb & 127;
    int m0  = (tl >> 5) * 128;
    int n0  = (tl & 31) * 128;
    const unsigned short* Ag = Pg + (size_t)bb * S_ * S_ + (size_t)m0 * S_;
    const unsigned short* Bg = (const unsigned short*)Vg + (size_t)bb * S_ * D_ + n0;
    int t = threadIdx.x;
    int w = t >> 6, l = t & 63, q = l >> 4, l15 = l & 15;
    int wm = w >> 1, wn = w & 1;
    float4v acc[4][4] = {};
    for (int k0 = 0; k0 < S_; k0 += 64) {
        __syncthreads();
        stage_tile<256>(ldsA, Ag + k0, S_, t);
        stage_vt(ldsB, Bg + (size_t)k0 * D_, t);
        __syncthreads();
        #pragma unroll
        for (int kc = 0; kc < 2; ++kc) {
            int kB = kc * 64 + q * 16;
            short8v a[4], b[4];
            #pragma unroll
            for (int mt = 0; mt < 4; ++mt) a[mt] = frag_ld(ldsA, wm * 64 + mt * 16 + l15, kB);
            #pragma unroll
            for (int nt = 0; nt < 4; ++nt) b[nt] = frag_ld(ldsB, wn * 64 + nt * 16 + l15, kB);
            #pragma unroll
            for (int mt = 0; mt < 4; ++mt)
                #pragma unroll
                for (int nt = 0; nt < 4; ++nt)
                    acc[mt][nt] = __builtin_amdgcn_mfma_f32_16x16x32_bf16(
                        a[mt], b[nt], acc[mt][nt], 0, 0, 0);
        }
    }
    #pragma unroll
    for (int mt = 0; mt < 4; ++mt) {
        #pragma unroll
        for (int j = 0; j < 4; ++j) {
            int s = m0 + wm * 64 + mt * 16 + q * 4 + j;
            if (s >= S_) continue;
            int f  = bb * T_ + (s >> 6);
            int l6 = s & 63;
            #pragma unroll
            for (int nt = 0; nt < 4; ++nt) {
                int d = n0 + wn * 64 + nt * 16 + l15;
                int c = d >> 6, r = d & 63;
                int y  = ((l6 >> 3) << 3) + (r >> 3);
                int xx = ((l6 & 7) << 3) + (r & 7);
                FEAT[(((size_t)f * C_ + c) * H_ + y) * W_ + xx] =
                    __float2bfloat16(acc[mt][nt][j]);
            }
        }
    }
}

// ---------------------------------------------------------------------------
extern "C" void kernel_launch(void* const* d_in, const int* in_sizes, int n_in,
                              void* d_out, int out_size, void* d_ws, size_t ws_size,
                              hipStream_t stream)
{
    const float* x  = (const float*)d_in[0];
    const float* wq = (const float*)d_in[1];
    const float* bq = (const float*)d_in[2];
    const float* wk = (const float*)d_in[3];
    const float* bk = (const float*)d_in[4];
    const float* wv = (const float*)d_in[5];
    const float* bv = (const float*)d_in[6];
    const float* wc = (const float*)d_in[7];
    const float* bc = (const float*)d_in[8];
    float* out = (float*)d_out;

    __hip_bfloat16* Qb = (__hip_bfloat16*)d_ws;
    __hip_bfloat16* Kb = Qb + QKV_E;
    __hip_bfloat16* Vb = Kb + QKV_E;
    float* ATTN = (float*)(Vb + QKV_E);
    __hip_bfloat16* Wt_v = (__hip_bfloat16*)(ATTN + ATTN_E);
    __hip_bfloat16* Wt_c = Wt_v + 9 * 64 * 64;
    unsigned short* Pb   = (unsigned short*)Kb;   // aliases Kb (dead after qk)
    __hip_bfloat16* FEAT = Qb;                    // aliases Qb (dead after qk)

    prep_w<<<144, 256, 0, stream>>>(wv, Wt_v);
    prep_w<<<144, 256, 0, stream>>>(wc, Wt_c);

    conv_qk_unfold2<<<dim3(8, 8, NFR), 256, 0, stream>>>(x, wq, bq, wk, bk, Qb, Kb);
    conv_mfma2<true><<<dim3(16, NFR), 256, 0, stream>>>(x, Wt_v, bv, nullptr, Vb);
    gemm_qk_mfma<<<256, 512, 0, stream>>>(Qb, Kb, ATTN);
    softmax_rows<<<B_ * S_, 64, 0, stream>>>(ATTN, Pb);
    gemm_pv_mfma<<<2048, 256, 0, stream>>>(Pb, Vb, FEAT);
    conv_mfma2<false><<<dim3(16, NFR), 256, 0, stream>>>(FEAT, Wt_c, bc, x, out);
}

// Round 7
// 426.244 us; speedup vs baseline: 16.5694x; 1.0790x over previous
//
#include <hip/hip_runtime.h>
#include <hip/hip_bf16.h>

// ---------------------------------------------------------------------------
// globalAttention: b=16 t=7 c=64 h=w=64, P=8  ->  112 frames, S=448, D=4096
//   1) prep_w x2      : wv,wc fp32 [co][ci][3][3] -> bf16 Wt[r][co][ci]
//   2) conv_qk_unfold3: depthwise 3x3 conv (q,k); x staged via LDS (coalesced
//                       reads), 1KB contiguous wave stores (r3), r6 lever
//   3) conv_mfma2<V>  : dense conv v, MFMA implicit GEMM, Wt staged in LDS,
//                       4-row bands, 1 row/wave, 75.3KB LDS -> 2 blocks/CU
//   4) gemm_qk_mfma   : ATTN = (1/64) Q K^T   (bf16 MFMA, fp32 out)
//   5) softmax_rows   : row softmax -> bf16 P  (P aliases Kb)
//   6) gemm_pv_mfma   : FEAT[f][c][y][x] bf16 = P @ V   (V transposed in LDS)
//   7) conv_mfma2<C>  : dense conv c + bias + residual -> d_out (float4 stores)
// Workspace: Qb[58.7M] Kb[58.7M] Vb[58.7M] ATTN[12.8M] Wt[144K]
// P(bf16) aliases Kb; FEAT(bf16) aliases Qb. Total ~189.5 MiB.
// ---------------------------------------------------------------------------

namespace {
constexpr int NFR = 112;
constexpr int T_  = 7;
constexpr int B_  = 16;
constexpr int C_  = 64;
constexpr int H_  = 64;
constexpr int W_  = 64;
constexpr int S_  = 448;
constexpr int D_  = 4096;
constexpr size_t QKV_E = (size_t)B_ * S_ * D_;
constexpr size_t ATTN_E = (size_t)B_ * S_ * S_;
}

typedef __attribute__((ext_vector_type(8))) short short8v;
typedef __attribute__((ext_vector_type(4))) float float4v;

__device__ __forceinline__ float bfu2f(unsigned short u) {
    union { unsigned int i; float f; } v; v.i = ((unsigned int)u) << 16; return v.f;
}
__device__ __forceinline__ unsigned short f2bf(float f) {
    __hip_bfloat16 h = __float2bfloat16(f);
    return *reinterpret_cast<unsigned short*>(&h);
}

// element (r, k) of a Rx64-short tile lives at byte r*128 + ((2k)^((r&7)<<4))
__device__ __forceinline__ short8v frag_ld(const char* ldsb, int r, int kByte) {
    return *(const short8v*)(ldsb + r * 128 + (kByte ^ ((r & 7) << 4)));
}

// stage 128 rows x 64 shorts from g (row stride ldg shorts) into swizzled LDS
template<int NTHR>
__device__ __forceinline__ void stage_tile(char* ldsb, const unsigned short* g,
                                           int ldg, int t) {
    #pragma unroll
    for (int i = 0; i < 1024 / NTHR; ++i) {
        int e = i * NTHR + t;
        int r = e >> 3, c8 = (e & 7) * 8;
        short8v v = *(const short8v*)(g + (size_t)r * ldg + c8);
        *(short8v*)(ldsb + r * 128 + ((c8 * 2) ^ ((r & 7) << 4))) = v;
    }
}

// stage V[u][d] tile (64 u x 128 d) TRANSPOSED into LDS as [d][u] swizzled
__device__ __forceinline__ void stage_vt(char* ldsb, const unsigned short* g, int t) {
    int d0 = (t & 15) * 8;
    int u0 = (t >> 4) * 4;
    short8v r0 = *(const short8v*)(g + (size_t)(u0 + 0) * D_ + d0);
    short8v r1 = *(const short8v*)(g + (size_t)(u0 + 1) * D_ + d0);
    short8v r2 = *(const short8v*)(g + (size_t)(u0 + 2) * D_ + d0);
    short8v r3 = *(const short8v*)(g + (size_t)(u0 + 3) * D_ + d0);
    #pragma unroll
    for (int j = 0; j < 8; ++j) {
        unsigned int lo = (unsigned short)r0[j] | (((unsigned int)(unsigned short)r1[j]) << 16);
        unsigned int hi = (unsigned short)r2[j] | (((unsigned int)(unsigned short)r3[j]) << 16);
        int d = d0 + j;
        int byte = d * 128 + (((unsigned)(u0 * 2)) ^ ((d & 7) << 4));
        *(uint2*)(ldsb + byte) = uint2{lo, hi};
    }
}

// ---------------- 1) weight transpose: [co][ci][3][3] f32 -> [r][co][ci] bf16
__global__ __launch_bounds__(256) void prep_w(const float* __restrict__ wsrc,
                                              __hip_bfloat16* __restrict__ wdst)
{
    int t = blockIdx.x * 256 + threadIdx.x;
    if (t >= 9 * 64 * 64) return;
    int r = t >> 12, co = (t >> 6) & 63, ci = t & 63;
    wdst[t] = __float2bfloat16(wsrc[(co * 64 + ci) * 9 + r]);
}

// ---------------- 2) depthwise conv q,k + unfold, LDS-staged x --------------
// Block (py, oct8, frame). LDS slab: 8 ch x 10 rows x 67-word stride (fp32),
// halo cols/rows zeroed in LDS -> branch-free compute. Stores unchanged:
// lane=(cg,ky) so each wave store is 1KB contiguous in Q/K.
__global__ __launch_bounds__(256) void conv_qk_unfold3(
    const float* __restrict__ x,
    const float* __restrict__ wq, const float* __restrict__ bq,
    const float* __restrict__ wk, const float* __restrict__ bk,
    __hip_bfloat16* __restrict__ Q, __hip_bfloat16* __restrict__ K)
{
    __shared__ float xls[8][10][67];
    int py  = blockIdx.x;          // 0..7
    int oc8 = blockIdx.y;          // 0..7
    int f   = blockIdx.z;          // 0..111
    int t = threadIdx.x;
    int yb = py * 8 - 1;

    // stage: coalesced 64-col rows; zero out-of-range rows
    for (int e = t; e < 8 * 10 * 64; e += 256) {
        int col = e & 63;
        int row = (e >> 6) % 10;
        int ch  = e / 640;
        int y = yb + row;
        float v = 0.f;
        if ((unsigned)y < (unsigned)H_)
            v = x[(((size_t)f * C_ + oc8 * 8 + ch) * H_ + y) * W_ + col];
        xls[ch][row][col + 1] = v;
    }
    // zero halo cols 0, 65, 66
    for (int e = t; e < 8 * 10 * 3; e += 256) {
        int which = e % 3;
        int row = (e / 3) % 10;
        int ch  = e / 30;
        xls[ch][row][which == 0 ? 0 : 64 + which] = 0.f;
    }
    __syncthreads();

    int w = t >> 6, lane = t & 63;
    int cg = lane >> 3, ky = lane & 7;
    int c  = oc8 * 8 + cg;
    float wqr[9], wkr[9];
    #pragma unroll
    for (int i = 0; i < 9; ++i) { wqr[i] = wq[c * 9 + i]; wkr[i] = wk[c * 9 + i]; }
    float bqv = bq[c], bkv = bk[c];
    int b = f / T_, tt = f % T_;
    unsigned short* Qp = (unsigned short*)Q;
    unsigned short* Kp = (unsigned short*)K;

    #pragma unroll
    for (int pi = 0; pi < 2; ++pi) {
        int px = w + pi * 4;
        int xb = px * 8;
        float acq[8], ack[8];
        #pragma unroll
        for (int j = 0; j < 8; ++j) { acq[j] = bqv; ack[j] = bkv; }
        #pragma unroll
        for (int dy = 0; dy < 3; ++dy) {
            const float* rp = &xls[cg][ky + dy][xb];   // cols xb-1 .. xb+8
            float r[10];
            #pragma unroll
            for (int j = 0; j < 10; ++j) r[j] = rp[j];
            float w0q = wqr[dy * 3], w1q = wqr[dy * 3 + 1], w2q = wqr[dy * 3 + 2];
            float w0k = wkr[dy * 3], w1k = wkr[dy * 3 + 1], w2k = wkr[dy * 3 + 2];
            #pragma unroll
            for (int j = 0; j < 8; ++j) {
                acq[j] += w0q * r[j] + w1q * r[j + 1] + w2q * r[j + 2];
                ack[j] += w0k * r[j] + w1k * r[j + 1] + w2k * r[j + 2];
            }
        }
        int s = tt * 64 + py * 8 + px;
        size_t off = ((size_t)b * S_ + s) * D_ + (size_t)c * 64 + ky * 8;
        unsigned short pq[8], pk[8];
        #pragma unroll
        for (int j = 0; j < 8; ++j) { pq[j] = f2bf(acq[j]); pk[j] = f2bf(ack[j]); }
        *(short8v*)(Qp + off) = *(const short8v*)pq;
        *(short8v*)(Kp + off) = *(const short8v*)pk;
    }
}

// ---------------- 3/7) dense 3x3 conv: implicit-GEMM MFMA, Wt in LDS --------
// Block: frame x 4-row band. 4 waves; wave w owns output row y0+w.
// Per wave: M=64 (x) x N=64 (co), K=576. A=x-frag, B=W-frag so C/D col=co,
// row=x -> coalesced stores. LDS: xs[6][66][128B] + wl[3][64][128B] = 75.3KB
// -> 2 blocks/CU (8 waves/CU); grid 16x112 = 7 blocks/CU exact.
template<bool IS_V>
__global__ __launch_bounds__(256, 2) void conv_mfma2(
    const void* __restrict__ src,                 // IS_V: f32 x ; else bf16 FEAT
    const __hip_bfloat16* __restrict__ Wt,        // [9][64][64] bf16
    const float* __restrict__ bias,
    const float* __restrict__ xin,                // residual input (conv_c)
    void* __restrict__ dst)                       // IS_V: bf16 V ; else f32 out
{
    __shared__ char xs[6 * 66 * 128];             // 50688 B
    __shared__ char wl[3 * 64 * 128];             // 24576 B
    const int f    = blockIdx.y;
    const int band = blockIdx.x;                  // 0..15
    const int y0   = band * 4;
    const int tid  = threadIdx.x;
    const int lane = tid & 63;
    const int w    = tid >> 6;
    const int q    = lane >> 4;
    const int l15  = lane & 15;

    // ---- stage xs: input rows y0-1 .. y0+4
    for (int e = tid; e < 6 * 16 * 64; e += 256) {
        int x  = e & 63;
        int cg = (e >> 6) & 15;
        int r  = e >> 10;
        int y  = y0 - 1 + r;
        unsigned short p[4];
        if ((unsigned)y < (unsigned)H_) {
            #pragma unroll
            for (int j = 0; j < 4; ++j) {
                size_t gi = (((size_t)f * C_ + cg * 4 + j) * H_ + y) * W_ + x;
                if constexpr (IS_V) p[j] = f2bf(((const float*)src)[gi]);
                else                p[j] = ((const unsigned short*)src)[gi];
            }
        } else { p[0] = p[1] = p[2] = p[3] = 0; }
        int xp = x + 1;
        int byte = (r * 66 + xp) * 128 + ((cg * 8) ^ ((xp & 7) << 4));
        *(uint2*)(xs + byte) = *(uint2*)p;
    }
    for (int e = tid; e < 6 * 16 * 2; e += 256) {
        int side = e & 1;
        int cg   = (e >> 1) & 15;
        int r    = e >> 5;
        int xp   = side ? 65 : 0;
        int byte = (r * 66 + xp) * 128 + ((cg * 8) ^ ((xp & 7) << 4));
        *(uint2*)(xs + byte) = uint2{0u, 0u};
    }

    float4v acc[4][4] = {};
    const unsigned short* Wg = (const unsigned short*)Wt;

    for (int ky = 0; ky < 3; ++ky) {
        __syncthreads();                          // protect wl from prev readers
        for (int i = tid; i < 1536; i += 256) {   // stage Wt slice (3 kx)
            int kx  = i >> 9;
            int rem = i & 511;
            int row = rem >> 3;
            int c8  = (rem & 7) * 8;
            short8v v = *(const short8v*)(Wg + ((ky * 3 + kx) * 4096 + row * 64 + c8));
            *(short8v*)(wl + kx * 8192 + row * 128 + ((c8 * 2) ^ ((row & 7) << 4))) = v;
        }
        __syncthreads();
        const int ri = w + ky;                    // xs row slot for this wave
        #pragma unroll
        for (int kx = 0; kx < 3; ++kx) {
            #pragma unroll
            for (int kc = 0; kc < 2; ++kc) {
                int kB = kc * 64 + q * 16;
                short8v bfr[4];
                #pragma unroll
                for (int nt = 0; nt < 4; ++nt)
                    bfr[nt] = frag_ld(wl + kx * 8192, nt * 16 + l15, kB);
                #pragma unroll
                for (int xt = 0; xt < 4; ++xt) {
                    int xp = xt * 16 + l15 + kx;
                    short8v av = *(const short8v*)(xs + (ri * 66 + xp) * 128 +
                                                   (kB ^ ((xp & 7) << 4)));
                    #pragma unroll
                    for (int nt = 0; nt < 4; ++nt)
                        acc[xt][nt] = __builtin_amdgcn_mfma_f32_16x16x32_bf16(
                            av, bfr[nt], acc[xt][nt], 0, 0, 0);
                }
            }
        }
    }

    // ---- epilogue: D col(l15)=co, row(q*4+j)=x
    float bco[4];
    #pragma unroll
    for (int nt = 0; nt < 4; ++nt) bco[nt] = bias[nt * 16 + l15];
    const int bb = f / T_, tt = f % T_;
    const int R = y0 + w;
    #pragma unroll
    for (int xt = 0; xt < 4; ++xt) {
        #pragma unroll
        for (int nt = 0; nt < 4; ++nt) {
            int co = nt * 16 + l15;
            if constexpr (IS_V) {
                int s  = tt * 64 + (R >> 3) * 8 + xt * 2 + (q >> 1);
                int d0 = co * 64 + (R & 7) * 8 + (q & 1) * 4;
                unsigned short pk[4];
                #pragma unroll
                for (int j = 0; j < 4; ++j)
                    pk[j] = f2bf(acc[xt][nt][j] + bco[nt]);
                *(uint2*)((unsigned short*)dst + ((size_t)bb * S_ + s) * D_ + d0) =
                    *(const uint2*)pk;
            } else {
                size_t o = (((size_t)f * C_ + co) * H_ + R) * W_ + xt * 16 + q * 4;
                float4 rv = *(const float4*)(xin + o);
                float4 ov;
                ov.x = acc[xt][nt][0] + bco[nt] + rv.x;
                ov.y = acc[xt][nt][1] + bco[nt] + rv.y;
                ov.z = acc[xt][nt][2] + bco[nt] + rv.z;
                ov.w = acc[xt][nt][3] + bco[nt] + rv.w;
                *(float4*)((float*)dst + o) = ov;
            }
        }
    }
}

// ---------------- 4) ATTN = (1/64) Q K^T via MFMA ---------------------------
__global__ __launch_bounds__(512, 2) void gemm_qk_mfma(
    const __hip_bfloat16* __restrict__ Qg,
    const __hip_bfloat16* __restrict__ Kg,
    float* __restrict__ ATTN)
{
    __shared__ alignas(16) char lds[32768];
    char* ldsA = lds;
    char* ldsB = lds + 16384;
    int bid = blockIdx.x;
    int lb  = (bid & 7) * 32 + (bid >> 3);
    int bb  = lb >> 4;
    int m0  = ((lb >> 2) & 3) * 128;
    int n0  = (lb & 3) * 128;
    const unsigned short* Ag = (const unsigned short*)Qg + (size_t)bb * S_ * D_ + (size_t)m0 * D_;
    const unsigned short* Bg = (const unsigned short*)Kg + (size_t)bb * S_ * D_ + (size_t)n0 * D_;
    int t = threadIdx.x;
    int w = t >> 6, l = t & 63, q = l >> 4, l15 = l & 15;
    int wm = w >> 2, wn = w & 3;
    int r0 = t >> 3, c0 = (t & 7) * 8;
    int r1 = 64 + r0;
    short8v sA0, sA1, sB0, sB1;
    sA0 = *(const short8v*)(Ag + (size_t)r0 * D_ + c0);
    sA1 = *(const short8v*)(Ag + (size_t)r1 * D_ + c0);
    sB0 = *(const short8v*)(Bg + (size_t)r0 * D_ + c0);
    sB1 = *(const short8v*)(Bg + (size_t)r1 * D_ + c0);

    float4v acc[4][2] = {};
    int swz0 = (c0 * 2) ^ ((r0 & 7) << 4);
    for (int k0 = 0; k0 < D_; k0 += 64) {
        __syncthreads();
        *(short8v*)(ldsA + r0 * 128 + swz0) = sA0;
        *(short8v*)(ldsA + r1 * 128 + swz0) = sA1;
        *(short8v*)(ldsB + r0 * 128 + swz0) = sB0;
        *(short8v*)(ldsB + r1 * 128 + swz0) = sB1;
        if (k0 + 64 < D_) {
            int kn = k0 + 64;
            sA0 = *(const short8v*)(Ag + (size_t)r0 * D_ + kn + c0);
            sA1 = *(const short8v*)(Ag + (size_t)r1 * D_ + kn + c0);
            sB0 = *(const short8v*)(Bg + (size_t)r0 * D_ + kn + c0);
            sB1 = *(const short8v*)(Bg + (size_t)r1 * D_ + kn + c0);
        }
        __syncthreads();
        #pragma unroll
        for (int kc = 0; kc < 2; ++kc) {
            int kB = kc * 64 + q * 16;
            short8v a[4], b[2];
            #pragma unroll
            for (int mt = 0; mt < 4; ++mt) a[mt] = frag_ld(ldsA, wm * 64 + mt * 16 + l15, kB);
            #pragma unroll
            for (int nt = 0; nt < 2; ++nt) b[nt] = frag_ld(ldsB, wn * 32 + nt * 16 + l15, kB);
            #pragma unroll
            for (int mt = 0; mt < 4; ++mt)
                #pragma unroll
                for (int nt = 0; nt < 2; ++nt)
                    acc[mt][nt] = __builtin_amdgcn_mfma_f32_16x16x32_bf16(
                        a[mt], b[nt], acc[mt][nt], 0, 0, 0);
        }
    }
    const float scale = 1.0f / 64.0f;
    #pragma unroll
    for (int mt = 0; mt < 4; ++mt) {
        #pragma unroll
        for (int nt = 0; nt < 2; ++nt) {
            int u = n0 + wn * 32 + nt * 16 + l15;
            #pragma unroll
            for (int j = 0; j < 4; ++j) {
                int s = m0 + wm * 64 + mt * 16 + q * 4 + j;
                if (s < S_ && u < S_)
                    ATTN[((size_t)bb * S_ + s) * S_ + u] = acc[mt][nt][j] * scale;
            }
        }
    }
}

// ---------------- 5) row softmax -> bf16 P ----------------------------------
__global__ __launch_bounds__(64) void softmax_rows(const float* __restrict__ ATTN,
                                                   unsigned short* __restrict__ P)
{
    size_t row = blockIdx.x;
    const float* p = ATTN + row * S_;
    int lane = threadIdx.x;
    float vals[7];
    float m = -1e30f;
    #pragma unroll
    for (int i = 0; i < 7; ++i) { vals[i] = p[lane + i * 64]; m = fmaxf(m, vals[i]); }
    #pragma unroll
    for (int off = 32; off; off >>= 1) m = fmaxf(m, __shfl_xor(m, off));
    float sum = 0.f;
    #pragma unroll
    for (int i = 0; i < 7; ++i) { vals[i] = __expf(vals[i] - m); sum += vals[i]; }
    #pragma unroll
    for (int off = 32; off; off >>= 1) sum += __shfl_xor(sum, off);
    float inv = 1.f / sum;
    #pragma unroll
    for (int i = 0; i < 7; ++i) P[row * S_ + lane + i * 64] = f2bf(vals[i] * inv);
}

// ---------------- 6) FEAT = P @ V via MFMA (V transposed in LDS) ------------
__global__ __launch_bounds__(256, 2) void gemm_pv_mfma(
    const unsigned short* __restrict__ Pg,
    const __hip_bfloat16* __restrict__ Vg,
    __hip_bfloat16* __restrict__ FEAT)
{
    __shared__ alignas(16) char lds[32768];
    char* ldsA = lds;
    char* ldsB = lds + 16384;
    int bid = blockIdx.x;
    int lb  = (bid & 7) * 256 + (bid >> 3);
    int bb  = lb >> 7;
    int tl  = lb & 127;
    int m0  = (tl >> 5) * 128;
    int n0  = (tl & 31) * 128;
    const unsigned short* Ag = Pg + (size_t)bb * S_ * S_ + (size_t)m0 * S_;
    const unsigned short* Bg = (const unsigned short*)Vg + (size_t)bb * S_ * D_ + n0;
    int t = threadIdx.x;
    int w = t >> 6, l = t & 63, q = l >> 4, l15 = l & 15;
    int wm = w >> 1, wn = w & 1;
    float4v acc[4][4] = {};
    for (int k0 = 0; k0 < S_; k0 += 64) {
        __syncthreads();
        stage_tile<256>(ldsA, Ag + k0, S_, t);
        stage_vt(ldsB, Bg + (size_t)k0 * D_, t);
        __syncthreads();
        #pragma unroll
        for (int kc = 0; kc < 2; ++kc) {
            int kB = kc * 64 + q * 16;
            short8v a[4], b[4];
            #pragma unroll
            for (int mt = 0; mt < 4; ++mt) a[mt] = frag_ld(ldsA, wm * 64 + mt * 16 + l15, kB);
            #pragma unroll
            for (int nt = 0; nt < 4; ++nt) b[nt] = frag_ld(ldsB, wn * 64 + nt * 16 + l15, kB);
            #pragma unroll
            for (int mt = 0; mt < 4; ++mt)
                #pragma unroll
                for (int nt = 0; nt < 4; ++nt)
                    acc[mt][nt] = __builtin_amdgcn_mfma_f32_16x16x32_bf16(
                        a[mt], b[nt], acc[mt][nt], 0, 0, 0);
        }
    }
    #pragma unroll
    for (int mt = 0; mt < 4; ++mt) {
        #pragma unroll
        for (int j = 0; j < 4; ++j) {
            int s = m0 + wm * 64 + mt * 16 + q * 4 + j;
            if (s >= S_) continue;
            int f  = bb * T_ + (s >> 6);
            int l6 = s & 63;
            #pragma unroll
            for (int nt = 0; nt < 4; ++nt) {
                int d = n0 + wn * 64 + nt * 16 + l15;
                int c = d >> 6, r = d & 63;
                int y  = ((l6 >> 3) << 3) + (r >> 3);
                int xx = ((l6 & 7) << 3) + (r & 7);
                FEAT[(((size_t)f * C_ + c) * H_ + y) * W_ + xx] =
                    __float2bfloat16(acc[mt][nt][j]);
            }
        }
    }
}

// ---------------------------------------------------------------------------
extern "C" void kernel_launch(void* const* d_in, const int* in_sizes, int n_in,
                              void* d_out, int out_size, void* d_ws, size_t ws_size,
                              hipStream_t stream)
{
    const float* x  = (const float*)d_in[0];
    const float* wq = (const float*)d_in[1];
    const float* bq = (const float*)d_in[2];
    const float* wk = (const float*)d_in[3];
    const float* bk = (const float*)d_in[4];
    const float* wv = (const float*)d_in[5];
    const float* bv = (const float*)d_in[6];
    const float* wc = (const float*)d_in[7];
    const float* bc = (const float*)d_in[8];
    float* out = (float*)d_out;

    __hip_bfloat16* Qb = (__hip_bfloat16*)d_ws;
    __hip_bfloat16* Kb = Qb + QKV_E;
    __hip_bfloat16* Vb = Kb + QKV_E;
    float* ATTN = (float*)(Vb + QKV_E);
    __hip_bfloat16* Wt_v = (__hip_bfloat16*)(ATTN + ATTN_E);
    __hip_bfloat16* Wt_c = Wt_v + 9 * 64 * 64;
    unsigned short* Pb   = (unsigned short*)Kb;   // aliases Kb (dead after qk)
    __hip_bfloat16* FEAT = Qb;                    // aliases Qb (dead after qk)

    prep_w<<<144, 256, 0, stream>>>(wv, Wt_v);
    prep_w<<<144, 256, 0, stream>>>(wc, Wt_c);

    conv_qk_unfold3<<<dim3(8, 8, NFR), 256, 0, stream>>>(x, wq, bq, wk, bk, Qb, Kb);
    conv_mfma2<true><<<dim3(16, NFR), 256, 0, stream>>>(x, Wt_v, bv, nullptr, Vb);
    gemm_qk_mfma<<<256, 512, 0, stream>>>(Qb, Kb, ATTN);
    softmax_rows<<<B_ * S_, 64, 0, stream>>>(ATTN, Pb);
    gemm_pv_mfma<<<2048, 256, 0, stream>>>(Pb, Vb, FEAT);
    conv_mfma2<false><<<dim3(16, NFR), 256, 0, stream>>>(FEAT, Wt_c, bc, x, out);
}